// Round 2
// baseline (922.949 us; speedup 1.0000x reference)
//
#include <hip/hip_runtime.h>
#include <hip/hip_bf16.h>

// Problem constants
#define NB 4
#define NC 256
#define NH_ 8
#define LPOOL 1024          // 32*32
constexpr float EPSV = 1e-5f;

typedef unsigned short ushort_t;
typedef __attribute__((ext_vector_type(8))) short bf16x8;
typedef __attribute__((ext_vector_type(4))) float f32x4;

// workspace offsets (in floats)
#define OFF_P   0u                  // pooled/normed: 2*4*256*1024 = 2,097,152 (reused for bf16 q/k + v2t after dwbn)
#define OFF_V2T 1048576u            // v2 transposed bf16 [n][c][s]: 1,048,576 ushorts = 524,288 float slots
#define OFF_Q   2097152u            // 1,048,576 each
#define OFF_K   3145728u
#define OFF_V1  4194304u
#define OFF_V2  5242880u
#define OFF_M1  6291456u
#define OFF_M2  7340032u
#define OFF_MG  8388608u
#define OFF_A   9437184u            // RegionA: scores bf16 (33.5M ushorts = 16.7M f-slots) -> z bf16
#define OFF_W1B 26214400u           // bf16 w1: 262144 ushorts = 131072 float slots (after scores)
#define OFF_W2B 26345472u           // bf16 w2: 131072 ushorts =  65536 float slots

__device__ __forceinline__ float bf16_to_f(unsigned short u) {
    union { unsigned int ui; float f; } t; t.ui = ((unsigned int)u) << 16; return t.f;
}
__device__ __forceinline__ unsigned short f_to_bf16(float f) {
    union { float f; unsigned int u; } t; t.f = f;
    unsigned int u = t.u;
    u += 0x7fffu + ((u >> 16) & 1u);
    return (unsigned short)(u >> 16);
}

// ---------------- maxpool 4x4 (both branches) ----------------
__global__ __launch_bounds__(256) void pool_kernel(const float* __restrict__ x1,
                                                   const float* __restrict__ x2,
                                                   float* __restrict__ pooled) {
    int idx = blockIdx.x * 256 + threadIdx.x;           // 2^21 total
    int j = idx & 31, i = (idx >> 5) & 31, c = (idx >> 10) & 255, n = (idx >> 18) & 3, br = idx >> 20;
    const float* xp = br ? x2 : x1;
    const float* base = xp + (((size_t)(n * 256 + c) * 128 + i * 4) * 128 + j * 4);
    float m = -3.4e38f;
#pragma unroll
    for (int r = 0; r < 4; ++r) {
        float4 v = *(const float4*)(base + r * 128);
        m = fmaxf(m, fmaxf(fmaxf(v.x, v.y), fmaxf(v.z, v.w)));
    }
    pooled[(size_t)br * 1048576 + (size_t)(n * 256 + c) * 1024 + i * 32 + j] = m;
}

// ---------------- LayerNorm over channel dim, in place ----------------
__global__ __launch_bounds__(256) void lnc_kernel(float* __restrict__ p,
                                                  const float* __restrict__ g,
                                                  const float* __restrict__ b) {
    int bid = blockIdx.x;                                // (br,n,l)
    int l = bid & 1023, n = (bid >> 10) & 3, br = bid >> 12;
    int c = threadIdx.x;
    size_t idx = (size_t)br * 1048576 + (size_t)(n * 256 + c) * 1024 + l;
    float v = p[idx];
    __shared__ float red[256];
    red[c] = v; __syncthreads();
    for (int off = 128; off > 0; off >>= 1) { if (c < off) red[c] += red[c + off]; __syncthreads(); }
    float mean = red[0] / 256.f;
    __syncthreads();
    float d = v - mean;
    red[c] = d * d; __syncthreads();
    for (int off = 128; off > 0; off >>= 1) { if (c < off) red[c] += red[c + off]; __syncthreads(); }
    float var = red[0] / 256.f;
    float rstd = rsqrtf(var + EPSV);
    p[idx] = (v - mean) * rstd * g[c] + b[c];
}

// ---------------- depthwise 3x3 conv + BN; writes heads layout [n][l][c] ----------------
__global__ __launch_bounds__(256) void dwbn_kernel(const float* __restrict__ p,
    const float* __restrict__ qkw, const float* __restrict__ qkg, const float* __restrict__ qkb,
    const float* __restrict__ qkm, const float* __restrict__ qkv,
    const float* __restrict__ vw, const float* __restrict__ vg, const float* __restrict__ vb,
    const float* __restrict__ vm, const float* __restrict__ vv,
    float* __restrict__ qkvbuf) {
    int which = blockIdx.y;                        // 0:q(p1,qk) 1:k(p2,qk) 2:v1(p1,v) 3:v2(p2,v)
    int flat = blockIdx.x * 256 + threadIdx.x;     // 2^20
    int l = flat & 1023, c = (flat >> 10) & 255, n = flat >> 18;
    int br = which & 1;
    const float* w  = (which < 2) ? qkw : vw;
    const float* g  = (which < 2) ? qkg : vg;
    const float* bb = (which < 2) ? qkb : vb;
    const float* rm = (which < 2) ? qkm : vm;
    const float* rv = (which < 2) ? qkv : vv;
    int i = l >> 5, j = l & 31;
    const float* pin = p + (size_t)br * 1048576 + (size_t)(n * 256 + c) * 1024;
    float acc = 0.f;
#pragma unroll
    for (int ky = -1; ky <= 1; ++ky) {
        int yy = i + ky;
        if ((unsigned)yy < 32u) {
#pragma unroll
            for (int kx = -1; kx <= 1; ++kx) {
                int xx = j + kx;
                if ((unsigned)xx < 32u)
                    acc += pin[yy * 32 + xx] * w[c * 9 + (ky + 1) * 3 + (kx + 1)];
            }
        }
    }
    float sc = g[c] * rsqrtf(rv[c] + EPSV);
    qkvbuf[(size_t)which * 1048576 + (size_t)(n * 1024 + l) * 256 + c] = sc * (acc - rm[c]) + bb[c];
}

// ---------------- fp32 -> bf16 conversion ----------------
__global__ __launch_bounds__(256) void cvt_kernel(const float* __restrict__ in,
                                                  ushort_t* __restrict__ out, int n) {
    int i = blockIdx.x * 256 + threadIdx.x;
    if (i < n) out[i] = f_to_bf16(in[i]);
}

// ---------------- v2 [n][s][c] f32 -> v2t [n][c][s] bf16 (32x32 LDS tile transpose) ----------------
__global__ __launch_bounds__(256) void v2t_kernel(const float* __restrict__ v,
                                                  ushort_t* __restrict__ vt) {
    int bid = blockIdx.x;
    int sb = bid & 31, cb = (bid >> 5) & 7, n = bid >> 8;
    int tid = threadIdx.x;
    __shared__ float t[32][33];
    int ci = tid & 31, sg = tid >> 5;
#pragma unroll
    for (int p = 0; p < 4; ++p) {
        int s = sb * 32 + p * 8 + sg;
        t[p * 8 + sg][ci] = v[(size_t)(n * 1024 + s) * 256 + cb * 32 + ci];
    }
    __syncthreads();
    int si = tid & 31, cg = tid >> 5;
#pragma unroll
    for (int p = 0; p < 4; ++p) {
        int c = cb * 32 + p * 8 + cg;
        vt[(size_t)(n * 256 + c) * 1024 + sb * 32 + si] = f_to_bf16(t[si][p * 8 + cg]);
    }
}

// ---------------- scores[n][h][l][s] (bf16) = t * Q_h K_h^T via MFMA bf16 ----------------
// grid (8 lt, 8 st, 32 nh); 128x128 tile per block, single K=32 step.
// Stores bf16, packed 2-per-u32 via lane-pairing (even ml lanes store).
__global__ __launch_bounds__(256) void qk_mfma(const ushort_t* __restrict__ qb,
                                               const ushort_t* __restrict__ kb,
                                               ushort_t* __restrict__ scores) {
    int lt = blockIdx.x, st = blockIdx.y;
    int nh = blockIdx.z; int n = nh >> 3, h = nh & 7;
    int l0 = lt * 128, s0 = st * 128;
    __shared__ ushort_t Qs[128 * 32];
    __shared__ ushort_t Ks[128 * 32];
    int tid = threadIdx.x, lane = tid & 63, wv = tid >> 6;
    int wm = wv >> 1, wn = wv & 1;
    int ml = lane & 15, quad = lane >> 4;
#pragma unroll
    for (int c = 0; c < 2; ++c) {
        int g = c * 256 + tid;
        int row = g >> 2, seg = g & 3;
        const ushort_t* ga = qb + (size_t)(n * 1024 + l0 + row) * 256 + h * 32 + seg * 8;
        __builtin_amdgcn_global_load_lds((const __attribute__((address_space(1))) void*)ga,
                                         (__attribute__((address_space(3))) void*)&Qs[row * 32 + seg * 8], 16, 0, 0);
        const ushort_t* gk = kb + (size_t)(n * 1024 + s0 + row) * 256 + h * 32 + seg * 8;
        __builtin_amdgcn_global_load_lds((const __attribute__((address_space(1))) void*)gk,
                                         (__attribute__((address_space(3))) void*)&Ks[row * 32 + seg * 8], 16, 0, 0);
    }
    __syncthreads();
    f32x4 acc[4][4];
#pragma unroll
    for (int i = 0; i < 4; ++i)
#pragma unroll
        for (int j = 0; j < 4; ++j) acc[i][j] = (f32x4)(0.f);
    bf16x8 af[4], bfr[4];
#pragma unroll
    for (int mt = 0; mt < 4; ++mt)
        af[mt] = *(const bf16x8*)&Qs[(wm * 64 + mt * 16 + ml) * 32 + quad * 8];
#pragma unroll
    for (int nt = 0; nt < 4; ++nt)
        bfr[nt] = *(const bf16x8*)&Ks[(wn * 64 + nt * 16 + ml) * 32 + quad * 8];
#pragma unroll
    for (int mt = 0; mt < 4; ++mt)
#pragma unroll
        for (int nt = 0; nt < 4; ++nt)
            acc[mt][nt] = __builtin_amdgcn_mfma_f32_16x16x32_bf16(af[mt], bfr[nt], acc[mt][nt], 0, 0, 0);
    const float tsc = 0.17677669529663687f;   // 1/sqrt(32)
    ushort_t* sb = scores + (size_t)nh * 1024 * 1024;
#pragma unroll
    for (int mt = 0; mt < 4; ++mt)
#pragma unroll
        for (int nt = 0; nt < 4; ++nt) {
            int col = s0 + wn * 64 + nt * 16 + ml;
#pragma unroll
            for (int r = 0; r < 4; ++r) {
                int row = l0 + wm * 64 + mt * 16 + quad * 4 + r;
                unsigned short b = f_to_bf16(tsc * acc[mt][nt][r]);
                int partner = __shfl_xor((int)b, 1);
                if (!(ml & 1)) {
                    unsigned int pk = (unsigned int)b | ((unsigned int)partner << 16);
                    *(unsigned int*)&sb[(size_t)row * 1024 + col] = pk;
                }
            }
        }
}

// ---------------- m1[n,l,h,d] = softmax_s(sc) @ v2, single-pass no-max exp + MFMA ----------------
// Scores are bounded (|s| << 80) so exp cannot overflow f32; normalization by 1/rowsum at the end.
// Each wave owns 16 l-rows x all 1024 s. No LDS, no barriers. Scores are bf16.
__global__ __launch_bounds__(256) void m1_kernel(const ushort_t* __restrict__ scores,
                                                 const ushort_t* __restrict__ v2t,
                                                 float* __restrict__ m1out) {
    int lt = blockIdx.x, h = blockIdx.y, n = blockIdx.z;
    int tid = threadIdx.x, lane = tid & 63, wv = tid >> 6;
    int ml = lane & 15, quad = lane >> 4;
    int l0 = lt * 64 + wv * 16;
    const ushort_t* arow = scores + (size_t)((n * 8 + h) * 1024 + l0 + ml) * 1024 + quad * 8;
    const ushort_t* vb = v2t + (size_t)(n * 256 + h * 32) * 1024;
    const ushort_t* vrow0 = vb + (size_t)ml * 1024 + quad * 8;
    const ushort_t* vrow1 = vb + (size_t)(ml + 16) * 1024 + quad * 8;
    f32x4 acc0 = (f32x4)(0.f), acc1 = (f32x4)(0.f);
    float rsum = 0.f;
#pragma unroll 4
    for (int s0 = 0; s0 < 1024; s0 += 32) {
        bf16x8 sv = *(const bf16x8*)(arow + s0);
        float e0 = __expf(bf16_to_f((ushort_t)sv[0]));
        float e1 = __expf(bf16_to_f((ushort_t)sv[1]));
        float e2 = __expf(bf16_to_f((ushort_t)sv[2]));
        float e3 = __expf(bf16_to_f((ushort_t)sv[3]));
        float e4 = __expf(bf16_to_f((ushort_t)sv[4]));
        float e5 = __expf(bf16_to_f((ushort_t)sv[5]));
        float e6 = __expf(bf16_to_f((ushort_t)sv[6]));
        float e7 = __expf(bf16_to_f((ushort_t)sv[7]));
        rsum += ((e0 + e1) + (e2 + e3)) + ((e4 + e5) + (e6 + e7));
        bf16x8 af;
        af[0] = (short)f_to_bf16(e0); af[1] = (short)f_to_bf16(e1);
        af[2] = (short)f_to_bf16(e2); af[3] = (short)f_to_bf16(e3);
        af[4] = (short)f_to_bf16(e4); af[5] = (short)f_to_bf16(e5);
        af[6] = (short)f_to_bf16(e6); af[7] = (short)f_to_bf16(e7);
        bf16x8 b0 = *(const bf16x8*)(vrow0 + s0);
        bf16x8 b1 = *(const bf16x8*)(vrow1 + s0);
        acc0 = __builtin_amdgcn_mfma_f32_16x16x32_bf16(af, b0, acc0, 0, 0, 0);
        acc1 = __builtin_amdgcn_mfma_f32_16x16x32_bf16(af, b1, acc1, 0, 0, 0);
    }
    // combine partial row-sums across the 4 quads (each lane ends with row ml's total)
    rsum += __shfl_xor(rsum, 16);
    rsum += __shfl_xor(rsum, 32);
    // C layout: col = ml (d), row = quad*4 + r (l). Fetch the matching row's sum via shfl.
#pragma unroll
    for (int r = 0; r < 4; ++r) {
        int row = quad * 4 + r;
        float inv = 1.f / __shfl(rsum, row);
        size_t ob = (size_t)(n * 1024 + l0 + row) * 256 + h * 32;
        m1out[ob + ml] = acc0[r] * inv;
        m1out[ob + 16 + ml] = acc1[r] * inv;
    }
}

// ---------------- m2[n,s,h,d] = sum_l softmax_h(sc)[l,s,h] * v1[l, h*32+d] ----------------
// Thread-local h-softmax (8 values per (l,s) in registers); 2 barriers per 8 l. Scores bf16.
__global__ __launch_bounds__(256) void m2_kernel(const ushort_t* __restrict__ scores,
                                                 const float* __restrict__ v1,
                                                 float* __restrict__ m2out) {
    int st = blockIdx.x;       // 32 tiles of 32 s
    int lc = blockIdx.y;       // 8 chunks of 128 l
    int n  = blockIdx.z;
    int s0 = st * 32, tid = threadIdx.x;
    __shared__ float wls[8][8][32];   // [l_sub][h][s]
    float acc[32];
#pragma unroll
    for (int i = 0; i < 32; ++i) acc[i] = 0.f;
    int lA = tid >> 5, siA = tid & 31;        // phase A: (l_sub, s)
    int hB = tid >> 5;                        // phase B: c = tid, h = tid>>5
    const ushort_t* sbase = scores + (size_t)n * 8 * 1024 * 1024;
    int lend = lc * 128 + 128;
    for (int lb = lc * 128; lb < lend; lb += 8) {
        // Phase A: per-thread softmax over h for one (l,s)
        int l = lb + lA;
        float e[8];
        float mx = -3.4e38f;
#pragma unroll
        for (int h = 0; h < 8; ++h) {
            e[h] = bf16_to_f(sbase[((size_t)h * 1024 + l) * 1024 + s0 + siA]);
            mx = fmaxf(mx, e[h]);
        }
        float sum = 0.f;
#pragma unroll
        for (int h = 0; h < 8; ++h) { e[h] = expf(e[h] - mx); sum += e[h]; }
        float inv = 1.f / sum;
#pragma unroll
        for (int h = 0; h < 8; ++h) wls[lA][h][siA] = e[h] * inv;
        __syncthreads();
        // Phase B: accumulate 8 l values
#pragma unroll
        for (int ls = 0; ls < 8; ++ls) {
            float v1v = v1[(size_t)(n * 1024 + lb + ls) * 256 + tid];
#pragma unroll
            for (int s4 = 0; s4 < 8; ++s4) {
                float4 w4 = *(const float4*)&wls[ls][hB][s4 * 4];
                acc[s4 * 4]     += w4.x * v1v;
                acc[s4 * 4 + 1] += w4.y * v1v;
                acc[s4 * 4 + 2] += w4.z * v1v;
                acc[s4 * 4 + 3] += w4.w * v1v;
            }
        }
        __syncthreads();
    }
#pragma unroll
    for (int ss = 0; ss < 32; ++ss)
        atomicAdd(&m2out[(size_t)(n * 1024 + s0 + ss) * 256 + tid], acc[ss]);
}

// ---------------- merged[n,l,c] = sum_c' m[n,l,c'] * merge_w[c,c'] ----------------
__global__ __launch_bounds__(256) void merge_kernel(const float* __restrict__ m,
                                                    const float* __restrict__ mw,
                                                    float* __restrict__ merged) {
    int bid = blockIdx.x;
    int n = bid >> 7, lt = bid & 127;
    int l0 = lt * 8, tid = threadIdx.x;
    __shared__ float ms[8][260];
#pragma unroll
    for (int r = 0; r < 8; ++r) ms[r][tid] = m[(size_t)(n * 1024 + l0 + r) * 256 + tid];
    __syncthreads();
    float acc[8];
#pragma unroll
    for (int r = 0; r < 8; ++r) acc[r] = 0.f;
    const float4* wrow = (const float4*)(mw + (size_t)tid * 256);
    for (int c4 = 0; c4 < 64; ++c4) {
        float4 w4 = wrow[c4];
#pragma unroll
        for (int r = 0; r < 8; ++r) {
            float4 m4 = *(const float4*)&ms[r][c4 * 4];
            acc[r] += w4.x * m4.x + w4.y * m4.y + w4.z * m4.z + w4.w * m4.w;
        }
    }
#pragma unroll
    for (int r = 0; r < 8; ++r)
        merged[(size_t)(n * 1024 + l0 + r) * 256 + tid] = acc[r];
}

// ---------------- z[pix][512] (bf16) = concat(x NHWC, bilinear-up(merged)) ----------------
__global__ __launch_bounds__(256) void zbuild_kernel(const float* __restrict__ x,
                                                     const float* __restrict__ merged,
                                                     ushort_t* __restrict__ z) {
    int pix0 = blockIdx.x * 32;
    int n = pix0 >> 14, y = (pix0 >> 7) & 127, x0 = pix0 & 127;
    int tid = threadIdx.x;
    int ci = tid >> 5, xi = tid & 31;
    __shared__ float xs[256][33];
    for (int cc = 0; cc < 32; ++cc) {
        int c = cc * 8 + ci;
        xs[c][xi] = x[((size_t)(n * 256 + c) * 128 + y) * 128 + x0 + xi];
    }
    __syncthreads();
    float iy = y * 0.25f - 0.375f;
    int y0i = (int)floorf(iy);
    float fy = iy - (float)y0i;
    int y0c = max(y0i, 0), y1c = min(y0i + 1, 31);
    const float* mb = merged + (size_t)n * 1024 * 256;
    for (int xj = 0; xj < 32; ++xj) {
        size_t zb = (size_t)(pix0 + xj) * 512;
        z[zb + tid] = f_to_bf16(xs[tid][xj]);
        int xx = x0 + xj;
        float ix = xx * 0.25f - 0.375f;
        int x0i = (int)floorf(ix);
        float fx = ix - (float)x0i;
        int x0cc = max(x0i, 0), x1cc = min(x0i + 1, 31);
        float v00 = mb[(size_t)(y0c * 32 + x0cc) * 256 + tid];
        float v01 = mb[(size_t)(y0c * 32 + x1cc) * 256 + tid];
        float v10 = mb[(size_t)(y1c * 32 + x0cc) * 256 + tid];
        float v11 = mb[(size_t)(y1c * 32 + x1cc) * 256 + tid];
        float v = (1.f - fy) * ((1.f - fx) * v00 + fx * v01) + fy * ((1.f - fx) * v10 + fx * v11);
        z[zb + 256 + tid] = f_to_bf16(v);
    }
}

// ---------------- fused MLP: hid=relu(Z@W1^T) in LDS; O=hid@W2^T in regs; LN+residual+NCHW write ----
// Per block: 64 pixels. Phase1: A/B fragments straight from global (Z streams, W1 L2-resident),
// hid bf16 [64][512] XOR-swizzled in LDS. Phase2: A from LDS, B (W2) from global. No K-loop barriers.
__global__ __launch_bounds__(256) void mlp_fused(const ushort_t* __restrict__ Z,
                                                 const ushort_t* __restrict__ W1,
                                                 const ushort_t* __restrict__ W2,
                                                 const float* __restrict__ xin,
                                                 const float* __restrict__ g2,
                                                 const float* __restrict__ b2,
                                                 float* __restrict__ outp) {
    __shared__ char smem[67584];
    float* olds = (float*)smem;                  // epilogue [64][257] f32 (overlays hid)
    float* redS = (float*)(smem + 65792);        // [64][2]
    float* redQ = (float*)(smem + 66304);        // [64][2]
    float* muA  = (float*)(smem + 66816);        // [64]
    float* rsA  = (float*)(smem + 67072);        // [64]

    int m0 = blockIdx.x * 64;
    int tid = threadIdx.x, lane = tid & 63, wv = tid >> 6;
    int ml = lane & 15, quad = lane >> 4;

    // ---- phase 1: hid[64][512] = relu(Z[m0..m0+63][512] @ W1^T); wave wv owns cols wv*128..+128
    {
        f32x4 acc[4][8];
#pragma unroll
        for (int i = 0; i < 4; ++i)
#pragma unroll
            for (int j = 0; j < 8; ++j) acc[i][j] = (f32x4)(0.f);
#pragma unroll 2
        for (int k0 = 0; k0 < 512; k0 += 32) {
            bf16x8 af[4], bfr[8];
#pragma unroll
            for (int mt = 0; mt < 4; ++mt)
                af[mt] = *(const bf16x8*)&Z[(size_t)(m0 + mt * 16 + ml) * 512 + k0 + quad * 8];
#pragma unroll
            for (int nt = 0; nt < 8; ++nt)
                bfr[nt] = *(const bf16x8*)&W1[(size_t)(wv * 128 + nt * 16 + ml) * 512 + k0 + quad * 8];
#pragma unroll
            for (int mt = 0; mt < 4; ++mt)
#pragma unroll
                for (int nt = 0; nt < 8; ++nt)
                    acc[mt][nt] = __builtin_amdgcn_mfma_f32_16x16x32_bf16(af[mt], bfr[nt], acc[mt][nt], 0, 0, 0);
        }
        // relu + bf16 -> LDS hid (XOR swizzle: byte ^= (row&7)<<4)
#pragma unroll
        for (int mt = 0; mt < 4; ++mt)
#pragma unroll
            for (int nt = 0; nt < 8; ++nt)
#pragma unroll
                for (int r = 0; r < 4; ++r) {
                    int row = mt * 16 + quad * 4 + r;
                    int col = wv * 128 + nt * 16 + ml;
                    unsigned byte = ((unsigned)(row * 512 + col) * 2u) ^ ((unsigned)(row & 7) << 4);
                    *(ushort_t*)(smem + byte) = f_to_bf16(fmaxf(acc[mt][nt][r], 0.f));
                }
    }
    __syncthreads();
    // ---- phase 2: O[64][256] = hid @ W2^T; 2x2 waves, wave tile 32x128
    int wm = wv >> 1, wn = wv & 1;
    f32x4 a2[2][8];
#pragma unroll
    for (int i = 0; i < 2; ++i)
#pragma unroll
        for (int j = 0; j < 8; ++j) a2[i][j] = (f32x4)(0.f);
#pragma unroll 2
    for (int k0 = 0; k0 < 512; k0 += 32) {
        bf16x8 af2[2], bf2[8];
#pragma unroll
        for (int mt = 0; mt < 2; ++mt) {
            int row = wm * 32 + mt * 16 + ml;
            unsigned byte = ((unsigned)(row * 1024 + k0 * 2 + quad * 16)) ^ ((unsigned)(row & 7) << 4);
            af2[mt] = *(const bf16x8*)(smem + byte);
        }
#pragma unroll
        for (int nt = 0; nt < 8; ++nt)
            bf2[nt] = *(const bf16x8*)&W2[(size_t)(wn * 128 + nt * 16 + ml) * 512 + k0 + quad * 8];
#pragma unroll
        for (int mt = 0; mt < 2; ++mt)
#pragma unroll
            for (int nt = 0; nt < 8; ++nt)
                a2[mt][nt] = __builtin_amdgcn_mfma_f32_16x16x32_bf16(af2[mt], bf2[nt], a2[mt][nt], 0, 0, 0);
    }
    // ---- LN stats: per-row sum/sumsq (wave covers 128 of 256 cols; reduce over ml then LDS)
#pragma unroll
    for (int mt = 0; mt < 2; ++mt)
#pragma unroll
        for (int r = 0; r < 4; ++r) {
            float s = 0.f, q = 0.f;
#pragma unroll
            for (int nt = 0; nt < 8; ++nt) { float v = a2[mt][nt][r]; s += v; q += v * v; }
            s += __shfl_xor(s, 1); s += __shfl_xor(s, 2); s += __shfl_xor(s, 4); s += __shfl_xor(s, 8);
            q += __shfl_xor(q, 1); q += __shfl_xor(q, 2); q += __shfl_xor(q, 4); q += __shfl_xor(q, 8);
            if (ml == 0) {
                int row = wm * 32 + mt * 16 + quad * 4 + r;
                redS[row * 2 + wn] = s; redQ[row * 2 + wn] = q;
            }
        }
    __syncthreads();
    if (tid < 64) {
        float S = redS[tid * 2] + redS[tid * 2 + 1];
        float Q = redQ[tid * 2] + redQ[tid * 2 + 1];
        float mu = S * (1.f / 256.f);
        float var = Q * (1.f / 256.f) - mu * mu;
        muA[tid] = mu; rsA[tid] = rsqrtf(var + EPSV);
    }
    __syncthreads();
    // ---- normalize -> padded LDS [64][257] (hid dead; all waves past the stats barrier)
    float gv[8], bv[8];
#pragma unroll
    for (int nt = 0; nt < 8; ++nt) {
        int col = wn * 128 + nt * 16 + ml;
        gv[nt] = g2[col]; bv[nt] = b2[col];
    }
#pragma unroll
    for (int mt = 0; mt < 2; ++mt)
#pragma unroll
        for (int r = 0; r < 4; ++r) {
            int row = wm * 32 + mt * 16 + quad * 4 + r;
            float mu = muA[row], rs = rsA[row];
#pragma unroll
            for (int nt = 0; nt < 8; ++nt) {
                int col = wn * 128 + nt * 16 + ml;
                olds[row * 257 + col] = (a2[mt][nt][r] - mu) * rs * gv[nt] + bv[nt];
            }
        }
    __syncthreads();
    // ---- residual + coalesced NCHW write
    int n = m0 >> 14, y = (m0 >> 7) & 127, x0 = m0 & 127;
    int cg = tid >> 5, xi = tid & 31;
    for (int cc = 0; cc < 32; ++cc) {
        int c = cc * 8 + cg;
        size_t gbase = ((size_t)(n * 256 + c) * 128 + y) * 128 + x0;
#pragma unroll
        for (int xc = 0; xc < 2; ++xc) {
            int p = xc * 32 + xi;
            outp[gbase + p] = xin[gbase + p] + olds[p * 257 + c];
        }
    }
}

extern "C" void kernel_launch(void* const* d_in, const int* in_sizes, int n_in,
                              void* d_out, int out_size, void* d_ws, size_t ws_size,
                              hipStream_t stream) {
    (void)in_sizes; (void)n_in; (void)out_size; (void)ws_size;
    const float* x1     = (const float*)d_in[0];
    const float* x2     = (const float*)d_in[1];
    const float* qk_w   = (const float*)d_in[2];
    const float* qk_g   = (const float*)d_in[3];
    const float* qk_b   = (const float*)d_in[4];
    const float* qk_m   = (const float*)d_in[5];
    const float* qk_v   = (const float*)d_in[6];
    const float* v_w    = (const float*)d_in[7];
    const float* v_g    = (const float*)d_in[8];
    const float* v_b    = (const float*)d_in[9];
    const float* v_m    = (const float*)d_in[10];
    const float* v_v    = (const float*)d_in[11];
    const float* ln1_g  = (const float*)d_in[12];
    const float* ln1_b  = (const float*)d_in[13];
    const float* ln2_g  = (const float*)d_in[14];
    const float* ln2_b  = (const float*)d_in[15];
    const float* merge_w = (const float*)d_in[16];
    const float* mlp_w1 = (const float*)d_in[17];
    const float* mlp_w2 = (const float*)d_in[18];

    float* ws      = (float*)d_ws;
    float* pooled  = ws + OFF_P;
    float* qkvbuf  = ws + OFF_Q;     // q,k,v1,v2 contiguous, 1,048,576 apart
    float* v1buf   = ws + OFF_V1;
    float* v2buf   = ws + OFF_V2;
    float* m1buf   = ws + OFF_M1;
    float* m2buf   = ws + OFF_M2;
    float* mgbuf   = ws + OFF_MG;
    ushort_t* scores16 = (ushort_t*)(ws + OFF_A); // scores bf16 -> z bf16 (stream-ordered reuse)
    ushort_t* qkb16 = (ushort_t*)(ws + OFF_P);   // q bf16 then k bf16 (pooled dead after dwbn)
    ushort_t* v2tb = (ushort_t*)(ws + OFF_V2T);  // v2 transposed bf16 (second half of dead pooled)
    ushort_t* zb16 = (ushort_t*)(ws + OFF_A);
    ushort_t* w1b  = (ushort_t*)(ws + OFF_W1B);
    ushort_t* w2b  = (ushort_t*)(ws + OFF_W2B);
    float* outp    = (float*)d_out;

    hipMemsetAsync(m2buf, 0, 1048576 * sizeof(float), stream);

    pool_kernel<<<8192, 256, 0, stream>>>(x1, x2, pooled);
    lnc_kernel<<<8192, 256, 0, stream>>>(pooled, ln1_g, ln1_b);
    dwbn_kernel<<<dim3(4096, 4), 256, 0, stream>>>(pooled,
        qk_w, qk_g, qk_b, qk_m, qk_v, v_w, v_g, v_b, v_m, v_v, qkvbuf);
    // q,k (contiguous at OFF_Q..OFF_K) -> bf16 into dead pooled region
    cvt_kernel<<<8192, 256, 0, stream>>>(qkvbuf, qkb16, 2097152);
    v2t_kernel<<<1024, 256, 0, stream>>>(v2buf, v2tb);
    qk_mfma<<<dim3(8, 8, 32), 256, 0, stream>>>(qkb16, qkb16 + 1048576, scores16);
    m1_kernel<<<dim3(16, 8, 4), 256, 0, stream>>>(scores16, v2tb, m1buf);
    m2_kernel<<<dim3(32, 8, 4), 256, 0, stream>>>(scores16, v1buf, m2buf);

    // weight conversion (after m1/m2: w1b/w2b live beyond the scores region)
    cvt_kernel<<<1024, 256, 0, stream>>>(mlp_w1, w1b, 262144);
    cvt_kernel<<<512, 256, 0, stream>>>(mlp_w2, w2b, 131072);

    for (int br = 0; br < 2; ++br) {
        const float* xin = br ? x2 : x1;
        const float* mm  = br ? m2buf : m1buf;
        merge_kernel<<<512, 256, 0, stream>>>(mm, merge_w, mgbuf);
        zbuild_kernel<<<2048, 256, 0, stream>>>(xin, mgbuf, zb16);
        mlp_fused<<<1024, 256, 0, stream>>>(zb16, w1b, w2b, xin, ln2_g, ln2_b,
                                            outp + (size_t)br * 16777216);
    }
}

// Round 3
// 767.361 us; speedup vs baseline: 1.2028x; 1.2028x over previous
//
#include <hip/hip_runtime.h>
#include <hip/hip_bf16.h>

// Problem constants
#define NB 4
#define NC 256
#define NH_ 8
#define LPOOL 1024          // 32*32
constexpr float EPSV = 1e-5f;

typedef unsigned short ushort_t;
typedef __attribute__((ext_vector_type(8))) short bf16x8;
typedef __attribute__((ext_vector_type(4))) float f32x4;

// workspace offsets (in floats)
#define OFF_P   0u                  // pooled/normed: 2*4*256*1024 = 2,097,152 (reused for bf16 q/k + v2t after dwbn)
#define OFF_V2T 1048576u            // v2 transposed bf16 [n][c][s]: 1,048,576 ushorts = 524,288 float slots
#define OFF_Q   2097152u            // 1,048,576 each
#define OFF_K   3145728u
#define OFF_V1  4194304u
#define OFF_V2  5242880u
#define OFF_M1  6291456u
#define OFF_M2  7340032u
#define OFF_MG  8388608u
#define OFF_A   9437184u            // RegionA: scores bf16 (33.5M ushorts = 16.7M f-slots) -> z bf16
#define OFF_W1B 26214400u           // bf16 w1: 262144 ushorts = 131072 float slots (after z region)
#define OFF_W2B 26345472u           // bf16 w2: 131072 ushorts =  65536 float slots
#define OFF_HID 26411008u           // hidden bf16: 33,554,432 ushorts = 16,777,216 float slots

__device__ __forceinline__ float bf16_to_f(unsigned short u) {
    union { unsigned int ui; float f; } t; t.ui = ((unsigned int)u) << 16; return t.f;
}
__device__ __forceinline__ unsigned short f_to_bf16(float f) {
    union { float f; unsigned int u; } t; t.f = f;
    unsigned int u = t.u;
    u += 0x7fffu + ((u >> 16) & 1u);
    return (unsigned short)(u >> 16);
}

// ---------------- maxpool 4x4 (both branches) ----------------
__global__ __launch_bounds__(256) void pool_kernel(const float* __restrict__ x1,
                                                   const float* __restrict__ x2,
                                                   float* __restrict__ pooled) {
    int idx = blockIdx.x * 256 + threadIdx.x;           // 2^21 total
    int j = idx & 31, i = (idx >> 5) & 31, c = (idx >> 10) & 255, n = (idx >> 18) & 3, br = idx >> 20;
    const float* xp = br ? x2 : x1;
    const float* base = xp + (((size_t)(n * 256 + c) * 128 + i * 4) * 128 + j * 4);
    float m = -3.4e38f;
#pragma unroll
    for (int r = 0; r < 4; ++r) {
        float4 v = *(const float4*)(base + r * 128);
        m = fmaxf(m, fmaxf(fmaxf(v.x, v.y), fmaxf(v.z, v.w)));
    }
    pooled[(size_t)br * 1048576 + (size_t)(n * 256 + c) * 1024 + i * 32 + j] = m;
}

// ---------------- LayerNorm over channel dim, in place ----------------
__global__ __launch_bounds__(256) void lnc_kernel(float* __restrict__ p,
                                                  const float* __restrict__ g,
                                                  const float* __restrict__ b) {
    int bid = blockIdx.x;                                // (br,n,l)
    int l = bid & 1023, n = (bid >> 10) & 3, br = bid >> 12;
    int c = threadIdx.x;
    size_t idx = (size_t)br * 1048576 + (size_t)(n * 256 + c) * 1024 + l;
    float v = p[idx];
    __shared__ float red[256];
    red[c] = v; __syncthreads();
    for (int off = 128; off > 0; off >>= 1) { if (c < off) red[c] += red[c + off]; __syncthreads(); }
    float mean = red[0] / 256.f;
    __syncthreads();
    float d = v - mean;
    red[c] = d * d; __syncthreads();
    for (int off = 128; off > 0; off >>= 1) { if (c < off) red[c] += red[c + off]; __syncthreads(); }
    float var = red[0] / 256.f;
    float rstd = rsqrtf(var + EPSV);
    p[idx] = (v - mean) * rstd * g[c] + b[c];
}

// ---------------- depthwise 3x3 conv + BN; writes heads layout [n][l][c] ----------------
__global__ __launch_bounds__(256) void dwbn_kernel(const float* __restrict__ p,
    const float* __restrict__ qkw, const float* __restrict__ qkg, const float* __restrict__ qkb,
    const float* __restrict__ qkm, const float* __restrict__ qkv,
    const float* __restrict__ vw, const float* __restrict__ vg, const float* __restrict__ vb,
    const float* __restrict__ vm, const float* __restrict__ vv,
    float* __restrict__ qkvbuf) {
    int which = blockIdx.y;                        // 0:q(p1,qk) 1:k(p2,qk) 2:v1(p1,v) 3:v2(p2,v)
    int flat = blockIdx.x * 256 + threadIdx.x;     // 2^20
    int l = flat & 1023, c = (flat >> 10) & 255, n = flat >> 18;
    int br = which & 1;
    const float* w  = (which < 2) ? qkw : vw;
    const float* g  = (which < 2) ? qkg : vg;
    const float* bb = (which < 2) ? qkb : vb;
    const float* rm = (which < 2) ? qkm : vm;
    const float* rv = (which < 2) ? qkv : vv;
    int i = l >> 5, j = l & 31;
    const float* pin = p + (size_t)br * 1048576 + (size_t)(n * 256 + c) * 1024;
    float acc = 0.f;
#pragma unroll
    for (int ky = -1; ky <= 1; ++ky) {
        int yy = i + ky;
        if ((unsigned)yy < 32u) {
#pragma unroll
            for (int kx = -1; kx <= 1; ++kx) {
                int xx = j + kx;
                if ((unsigned)xx < 32u)
                    acc += pin[yy * 32 + xx] * w[c * 9 + (ky + 1) * 3 + (kx + 1)];
            }
        }
    }
    float sc = g[c] * rsqrtf(rv[c] + EPSV);
    qkvbuf[(size_t)which * 1048576 + (size_t)(n * 1024 + l) * 256 + c] = sc * (acc - rm[c]) + bb[c];
}

// ---------------- fp32 -> bf16 conversion ----------------
__global__ __launch_bounds__(256) void cvt_kernel(const float* __restrict__ in,
                                                  ushort_t* __restrict__ out, int n) {
    int i = blockIdx.x * 256 + threadIdx.x;
    if (i < n) out[i] = f_to_bf16(in[i]);
}

// ---------------- v2 [n][s][c] f32 -> v2t [n][c][s] bf16 (32x32 LDS tile transpose) ----------------
__global__ __launch_bounds__(256) void v2t_kernel(const float* __restrict__ v,
                                                  ushort_t* __restrict__ vt) {
    int bid = blockIdx.x;
    int sb = bid & 31, cb = (bid >> 5) & 7, n = bid >> 8;
    int tid = threadIdx.x;
    __shared__ float t[32][33];
    int ci = tid & 31, sg = tid >> 5;
#pragma unroll
    for (int p = 0; p < 4; ++p) {
        int s = sb * 32 + p * 8 + sg;
        t[p * 8 + sg][ci] = v[(size_t)(n * 1024 + s) * 256 + cb * 32 + ci];
    }
    __syncthreads();
    int si = tid & 31, cg = tid >> 5;
#pragma unroll
    for (int p = 0; p < 4; ++p) {
        int c = cb * 32 + p * 8 + cg;
        vt[(size_t)(n * 256 + c) * 1024 + sb * 32 + si] = f_to_bf16(t[si][p * 8 + cg]);
    }
}

// ---------------- scores[n][h][l][s] (bf16) = t * Q_h K_h^T via MFMA bf16 ----------------
// grid (8 lt, 8 st, 32 nh); 128x128 tile per block, single K=32 step.
// Stores bf16, packed 2-per-u32 via lane-pairing (even ml lanes store).
__global__ __launch_bounds__(256) void qk_mfma(const ushort_t* __restrict__ qb,
                                               const ushort_t* __restrict__ kb,
                                               ushort_t* __restrict__ scores) {
    int lt = blockIdx.x, st = blockIdx.y;
    int nh = blockIdx.z; int n = nh >> 3, h = nh & 7;
    int l0 = lt * 128, s0 = st * 128;
    __shared__ ushort_t Qs[128 * 32];
    __shared__ ushort_t Ks[128 * 32];
    int tid = threadIdx.x, lane = tid & 63, wv = tid >> 6;
    int wm = wv >> 1, wn = wv & 1;
    int ml = lane & 15, quad = lane >> 4;
#pragma unroll
    for (int c = 0; c < 2; ++c) {
        int g = c * 256 + tid;
        int row = g >> 2, seg = g & 3;
        const ushort_t* ga = qb + (size_t)(n * 1024 + l0 + row) * 256 + h * 32 + seg * 8;
        __builtin_amdgcn_global_load_lds((const __attribute__((address_space(1))) void*)ga,
                                         (__attribute__((address_space(3))) void*)&Qs[row * 32 + seg * 8], 16, 0, 0);
        const ushort_t* gk = kb + (size_t)(n * 1024 + s0 + row) * 256 + h * 32 + seg * 8;
        __builtin_amdgcn_global_load_lds((const __attribute__((address_space(1))) void*)gk,
                                         (__attribute__((address_space(3))) void*)&Ks[row * 32 + seg * 8], 16, 0, 0);
    }
    __syncthreads();
    f32x4 acc[4][4];
#pragma unroll
    for (int i = 0; i < 4; ++i)
#pragma unroll
        for (int j = 0; j < 4; ++j) acc[i][j] = (f32x4)(0.f);
    bf16x8 af[4], bfr[4];
#pragma unroll
    for (int mt = 0; mt < 4; ++mt)
        af[mt] = *(const bf16x8*)&Qs[(wm * 64 + mt * 16 + ml) * 32 + quad * 8];
#pragma unroll
    for (int nt = 0; nt < 4; ++nt)
        bfr[nt] = *(const bf16x8*)&Ks[(wn * 64 + nt * 16 + ml) * 32 + quad * 8];
#pragma unroll
    for (int mt = 0; mt < 4; ++mt)
#pragma unroll
        for (int nt = 0; nt < 4; ++nt)
            acc[mt][nt] = __builtin_amdgcn_mfma_f32_16x16x32_bf16(af[mt], bfr[nt], acc[mt][nt], 0, 0, 0);
    const float tsc = 0.17677669529663687f;   // 1/sqrt(32)
    ushort_t* sb = scores + (size_t)nh * 1024 * 1024;
#pragma unroll
    for (int mt = 0; mt < 4; ++mt)
#pragma unroll
        for (int nt = 0; nt < 4; ++nt) {
            int col = s0 + wn * 64 + nt * 16 + ml;
#pragma unroll
            for (int r = 0; r < 4; ++r) {
                int row = l0 + wm * 64 + mt * 16 + quad * 4 + r;
                unsigned short b = f_to_bf16(tsc * acc[mt][nt][r]);
                int partner = __shfl_xor((int)b, 1);
                if (!(ml & 1)) {
                    unsigned int pk = (unsigned int)b | ((unsigned int)partner << 16);
                    *(unsigned int*)&sb[(size_t)row * 1024 + col] = pk;
                }
            }
        }
}

// ---------------- m1[n,l,h,d] = softmax_s(sc) @ v2, single-pass no-max exp + MFMA ----------------
// Scores are bounded (|s| << 80) so exp cannot overflow f32; normalization by 1/rowsum at the end.
// Each wave owns 16 l-rows x all 1024 s. No LDS, no barriers. Scores are bf16.
__global__ __launch_bounds__(256) void m1_kernel(const ushort_t* __restrict__ scores,
                                                 const ushort_t* __restrict__ v2t,
                                                 float* __restrict__ m1out) {
    int lt = blockIdx.x, h = blockIdx.y, n = blockIdx.z;
    int tid = threadIdx.x, lane = tid & 63, wv = tid >> 6;
    int ml = lane & 15, quad = lane >> 4;
    int l0 = lt * 64 + wv * 16;
    const ushort_t* arow = scores + (size_t)((n * 8 + h) * 1024 + l0 + ml) * 1024 + quad * 8;
    const ushort_t* vb = v2t + (size_t)(n * 256 + h * 32) * 1024;
    const ushort_t* vrow0 = vb + (size_t)ml * 1024 + quad * 8;
    const ushort_t* vrow1 = vb + (size_t)(ml + 16) * 1024 + quad * 8;
    f32x4 acc0 = (f32x4)(0.f), acc1 = (f32x4)(0.f);
    float rsum = 0.f;
#pragma unroll 4
    for (int s0 = 0; s0 < 1024; s0 += 32) {
        bf16x8 sv = *(const bf16x8*)(arow + s0);
        float e0 = __expf(bf16_to_f((ushort_t)sv[0]));
        float e1 = __expf(bf16_to_f((ushort_t)sv[1]));
        float e2 = __expf(bf16_to_f((ushort_t)sv[2]));
        float e3 = __expf(bf16_to_f((ushort_t)sv[3]));
        float e4 = __expf(bf16_to_f((ushort_t)sv[4]));
        float e5 = __expf(bf16_to_f((ushort_t)sv[5]));
        float e6 = __expf(bf16_to_f((ushort_t)sv[6]));
        float e7 = __expf(bf16_to_f((ushort_t)sv[7]));
        rsum += ((e0 + e1) + (e2 + e3)) + ((e4 + e5) + (e6 + e7));
        bf16x8 af;
        af[0] = (short)f_to_bf16(e0); af[1] = (short)f_to_bf16(e1);
        af[2] = (short)f_to_bf16(e2); af[3] = (short)f_to_bf16(e3);
        af[4] = (short)f_to_bf16(e4); af[5] = (short)f_to_bf16(e5);
        af[6] = (short)f_to_bf16(e6); af[7] = (short)f_to_bf16(e7);
        bf16x8 b0 = *(const bf16x8*)(vrow0 + s0);
        bf16x8 b1 = *(const bf16x8*)(vrow1 + s0);
        acc0 = __builtin_amdgcn_mfma_f32_16x16x32_bf16(af, b0, acc0, 0, 0, 0);
        acc1 = __builtin_amdgcn_mfma_f32_16x16x32_bf16(af, b1, acc1, 0, 0, 0);
    }
    // combine partial row-sums across the 4 quads (each lane ends with row ml's total)
    rsum += __shfl_xor(rsum, 16);
    rsum += __shfl_xor(rsum, 32);
    // C layout: col = ml (d), row = quad*4 + r (l). Fetch the matching row's sum via shfl.
#pragma unroll
    for (int r = 0; r < 4; ++r) {
        int row = quad * 4 + r;
        float inv = 1.f / __shfl(rsum, row);
        size_t ob = (size_t)(n * 1024 + l0 + row) * 256 + h * 32;
        m1out[ob + ml] = acc0[r] * inv;
        m1out[ob + 16 + ml] = acc1[r] * inv;
    }
}

// ---------------- m2[n,s,h,d] = sum_l softmax_h(sc)[l,s,h] * v1[l, h*32+d] ----------------
// Thread-local h-softmax (8 values per (l,s) in registers); 2 barriers per 8 l. Scores bf16.
__global__ __launch_bounds__(256) void m2_kernel(const ushort_t* __restrict__ scores,
                                                 const float* __restrict__ v1,
                                                 float* __restrict__ m2out) {
    int st = blockIdx.x;       // 32 tiles of 32 s
    int lc = blockIdx.y;       // 8 chunks of 128 l
    int n  = blockIdx.z;
    int s0 = st * 32, tid = threadIdx.x;
    __shared__ float wls[8][8][32];   // [l_sub][h][s]
    float acc[32];
#pragma unroll
    for (int i = 0; i < 32; ++i) acc[i] = 0.f;
    int lA = tid >> 5, siA = tid & 31;        // phase A: (l_sub, s)
    int hB = tid >> 5;                        // phase B: c = tid, h = tid>>5
    const ushort_t* sbase = scores + (size_t)n * 8 * 1024 * 1024;
    int lend = lc * 128 + 128;
    for (int lb = lc * 128; lb < lend; lb += 8) {
        // Phase A: per-thread softmax over h for one (l,s)
        int l = lb + lA;
        float e[8];
        float mx = -3.4e38f;
#pragma unroll
        for (int h = 0; h < 8; ++h) {
            e[h] = bf16_to_f(sbase[((size_t)h * 1024 + l) * 1024 + s0 + siA]);
            mx = fmaxf(mx, e[h]);
        }
        float sum = 0.f;
#pragma unroll
        for (int h = 0; h < 8; ++h) { e[h] = expf(e[h] - mx); sum += e[h]; }
        float inv = 1.f / sum;
#pragma unroll
        for (int h = 0; h < 8; ++h) wls[lA][h][siA] = e[h] * inv;
        __syncthreads();
        // Phase B: accumulate 8 l values
#pragma unroll
        for (int ls = 0; ls < 8; ++ls) {
            float v1v = v1[(size_t)(n * 1024 + lb + ls) * 256 + tid];
#pragma unroll
            for (int s4 = 0; s4 < 8; ++s4) {
                float4 w4 = *(const float4*)&wls[ls][hB][s4 * 4];
                acc[s4 * 4]     += w4.x * v1v;
                acc[s4 * 4 + 1] += w4.y * v1v;
                acc[s4 * 4 + 2] += w4.z * v1v;
                acc[s4 * 4 + 3] += w4.w * v1v;
            }
        }
        __syncthreads();
    }
#pragma unroll
    for (int ss = 0; ss < 32; ++ss)
        atomicAdd(&m2out[(size_t)(n * 1024 + s0 + ss) * 256 + tid], acc[ss]);
}

// ---------------- merged[n,l,c] = sum_c' m[n,l,c'] * merge_w[c,c'] ----------------
__global__ __launch_bounds__(256) void merge_kernel(const float* __restrict__ m,
                                                    const float* __restrict__ mw,
                                                    float* __restrict__ merged) {
    int bid = blockIdx.x;
    int n = bid >> 7, lt = bid & 127;
    int l0 = lt * 8, tid = threadIdx.x;
    __shared__ float ms[8][260];
#pragma unroll
    for (int r = 0; r < 8; ++r) ms[r][tid] = m[(size_t)(n * 1024 + l0 + r) * 256 + tid];
    __syncthreads();
    float acc[8];
#pragma unroll
    for (int r = 0; r < 8; ++r) acc[r] = 0.f;
    const float4* wrow = (const float4*)(mw + (size_t)tid * 256);
    for (int c4 = 0; c4 < 64; ++c4) {
        float4 w4 = wrow[c4];
#pragma unroll
        for (int r = 0; r < 8; ++r) {
            float4 m4 = *(const float4*)&ms[r][c4 * 4];
            acc[r] += w4.x * m4.x + w4.y * m4.y + w4.z * m4.z + w4.w * m4.w;
        }
    }
#pragma unroll
    for (int r = 0; r < 8; ++r)
        merged[(size_t)(n * 1024 + l0 + r) * 256 + tid] = acc[r];
}

// ---------------- z[pix][512] (bf16) = concat(x NHWC, bilinear-up(merged)) ----------------
__global__ __launch_bounds__(256) void zbuild_kernel(const float* __restrict__ x,
                                                     const float* __restrict__ merged,
                                                     ushort_t* __restrict__ z) {
    int pix0 = blockIdx.x * 32;
    int n = pix0 >> 14, y = (pix0 >> 7) & 127, x0 = pix0 & 127;
    int tid = threadIdx.x;
    int ci = tid >> 5, xi = tid & 31;
    __shared__ float xs[256][33];
    for (int cc = 0; cc < 32; ++cc) {
        int c = cc * 8 + ci;
        xs[c][xi] = x[((size_t)(n * 256 + c) * 128 + y) * 128 + x0 + xi];
    }
    __syncthreads();
    float iy = y * 0.25f - 0.375f;
    int y0i = (int)floorf(iy);
    float fy = iy - (float)y0i;
    int y0c = max(y0i, 0), y1c = min(y0i + 1, 31);
    const float* mb = merged + (size_t)n * 1024 * 256;
    for (int xj = 0; xj < 32; ++xj) {
        size_t zb = (size_t)(pix0 + xj) * 512;
        z[zb + tid] = f_to_bf16(xs[tid][xj]);
        int xx = x0 + xj;
        float ix = xx * 0.25f - 0.375f;
        int x0i = (int)floorf(ix);
        float fx = ix - (float)x0i;
        int x0cc = max(x0i, 0), x1cc = min(x0i + 1, 31);
        float v00 = mb[(size_t)(y0c * 32 + x0cc) * 256 + tid];
        float v01 = mb[(size_t)(y0c * 32 + x1cc) * 256 + tid];
        float v10 = mb[(size_t)(y1c * 32 + x0cc) * 256 + tid];
        float v11 = mb[(size_t)(y1c * 32 + x1cc) * 256 + tid];
        float v = (1.f - fy) * ((1.f - fx) * v00 + fx * v01) + fy * ((1.f - fx) * v10 + fx * v11);
        z[zb + 256 + tid] = f_to_bf16(v);
    }
}

// ---------------- MFMA bf16 GEMM: C[M,N] = act(A[M,512] @ B[N,512]^T) ----------------
__global__ __launch_bounds__(256) void mfma_gemm(const ushort_t* __restrict__ A,
                                                 const ushort_t* __restrict__ B,
                                                 float* __restrict__ Of,
                                                 ushort_t* __restrict__ Oh,
                                                 int N, int relu) {
    const int K = 512;
    int m0 = blockIdx.x * 128, n0 = blockIdx.y * 128;
    int tid = threadIdx.x;
    __shared__ ushort_t Al[128 * 32];
    __shared__ ushort_t Bl[128 * 32];
    int lane = tid & 63;
    int wv = tid >> 6;
    int wm = wv >> 1, wn = wv & 1;          // 2x2 wave grid -> 64x64 per wave
    int ml = lane & 15, quad = lane >> 4;
    f32x4 acc[4][4];
#pragma unroll
    for (int i = 0; i < 4; ++i)
#pragma unroll
        for (int j = 0; j < 4; ++j) acc[i][j] = (f32x4)(0.f);

    for (int k0 = 0; k0 < K; k0 += 32) {
#pragma unroll
        for (int c = 0; c < 2; ++c) {
            int g = c * 256 + tid;
            int row = g >> 2, seg = g & 3;
            const ushort_t* ga = A + (size_t)(m0 + row) * K + k0 + seg * 8;
            __builtin_amdgcn_global_load_lds((const __attribute__((address_space(1))) void*)ga,
                                             (__attribute__((address_space(3))) void*)&Al[g * 8], 16, 0, 0);
            const ushort_t* gb = B + (size_t)(n0 + row) * K + k0 + seg * 8;
            __builtin_amdgcn_global_load_lds((const __attribute__((address_space(1))) void*)gb,
                                             (__attribute__((address_space(3))) void*)&Bl[g * 8], 16, 0, 0);
        }
        __syncthreads();
        bf16x8 af[4], bfr[4];
#pragma unroll
        for (int mt = 0; mt < 4; ++mt)
            af[mt] = *(const bf16x8*)&Al[(wm * 64 + mt * 16 + ml) * 32 + quad * 8];
#pragma unroll
        for (int nt = 0; nt < 4; ++nt)
            bfr[nt] = *(const bf16x8*)&Bl[(wn * 64 + nt * 16 + ml) * 32 + quad * 8];
#pragma unroll
        for (int mt = 0; mt < 4; ++mt)
#pragma unroll
            for (int nt = 0; nt < 4; ++nt)
                acc[mt][nt] = __builtin_amdgcn_mfma_f32_16x16x32_bf16(af[mt], bfr[nt], acc[mt][nt], 0, 0, 0);
        __syncthreads();
    }
#pragma unroll
    for (int mt = 0; mt < 4; ++mt) {
#pragma unroll
        for (int nt = 0; nt < 4; ++nt) {
            int col = n0 + wn * 64 + nt * 16 + ml;
#pragma unroll
            for (int r = 0; r < 4; ++r) {
                int row = m0 + wm * 64 + mt * 16 + quad * 4 + r;
                float v = acc[mt][nt][r];
                if (relu) v = fmaxf(v, 0.f);
                if (Oh) Oh[(size_t)row * N + col] = f_to_bf16(v);
                else    Of[(size_t)row * N + col] = v;
            }
        }
    }
}

// ---------------- fused GEMM2 + LN + residual + NCHW write ----------------
// Per block: 64 pixels (rows) x all 256 channels (cols), K=512.
// K-loop mirrors mfma_gemm (global_load_lds staging, linear LDS). Wave wv owns cols wv*64..+64.
// Epilogue: LN stats via shfl+LDS, then two half-width transpose passes through LDS.
__global__ __launch_bounds__(256) void gemm2_ln(const ushort_t* __restrict__ hid,
                                                const ushort_t* __restrict__ W2,
                                                const float* __restrict__ xin,
                                                const float* __restrict__ g2,
                                                const float* __restrict__ b2,
                                                float* __restrict__ outp) {
    __shared__ char smem[35584];
    ushort_t* Al = (ushort_t*)smem;              // [64][32] bf16 = 4KB
    ushort_t* Bl = (ushort_t*)(smem + 4096);     // [256][32] bf16 = 16KB
    int m0 = blockIdx.x * 64;
    int tid = threadIdx.x, lane = tid & 63, wv = tid >> 6;
    int ml = lane & 15, quad = lane >> 4;
    f32x4 acc[4][4];
#pragma unroll
    for (int i = 0; i < 4; ++i)
#pragma unroll
        for (int j = 0; j < 4; ++j) acc[i][j] = (f32x4)(0.f);

    for (int k0 = 0; k0 < 512; k0 += 32) {
        {   // stage A: 64 rows x 32; one 16B load per thread (dest linear in tid)
            int row = tid >> 2, seg = tid & 3;
            const ushort_t* ga = hid + (size_t)(m0 + row) * 512 + k0 + seg * 8;
            __builtin_amdgcn_global_load_lds((const __attribute__((address_space(1))) void*)ga,
                                             (__attribute__((address_space(3))) void*)&Al[tid * 8], 16, 0, 0);
        }
#pragma unroll
        for (int c = 0; c < 4; ++c) {   // stage B: 256 rows x 32; four 16B loads per thread
            int g = c * 256 + tid;
            int row = g >> 2, seg = g & 3;
            const ushort_t* gb = W2 + (size_t)row * 512 + k0 + seg * 8;
            __builtin_amdgcn_global_load_lds((const __attribute__((address_space(1))) void*)gb,
                                             (__attribute__((address_space(3))) void*)&Bl[g * 8], 16, 0, 0);
        }
        __syncthreads();
        bf16x8 af[4], bfr[4];
#pragma unroll
        for (int mt = 0; mt < 4; ++mt)
            af[mt] = *(const bf16x8*)&Al[(mt * 16 + ml) * 32 + quad * 8];
#pragma unroll
        for (int nt = 0; nt < 4; ++nt)
            bfr[nt] = *(const bf16x8*)&Bl[(wv * 64 + nt * 16 + ml) * 32 + quad * 8];
#pragma unroll
        for (int mt = 0; mt < 4; ++mt)
#pragma unroll
            for (int nt = 0; nt < 4; ++nt)
                acc[mt][nt] = __builtin_amdgcn_mfma_f32_16x16x32_bf16(af[mt], bfr[nt], acc[mt][nt], 0, 0, 0);
        __syncthreads();
    }
    // ---- LN stats: per-row (pixel) sum/sumsq over 256 cols. Wave covers 64 cols.
    float* redS = (float*)smem;            // [64][4]
    float* redQ = (float*)(smem + 1024);   // [64][4]
    float* muA  = (float*)(smem + 2048);   // [64]
    float* rsA  = (float*)(smem + 2304);   // [64]
    float* olds = (float*)(smem + 2560);   // [64][129]
#pragma unroll
    for (int mt = 0; mt < 4; ++mt)
#pragma unroll
        for (int r = 0; r < 4; ++r) {
            float s = 0.f, q = 0.f;
#pragma unroll
            for (int nt = 0; nt < 4; ++nt) { float v = acc[mt][nt][r]; s += v; q += v * v; }
            s += __shfl_xor(s, 1); s += __shfl_xor(s, 2); s += __shfl_xor(s, 4); s += __shfl_xor(s, 8);
            q += __shfl_xor(q, 1); q += __shfl_xor(q, 2); q += __shfl_xor(q, 4); q += __shfl_xor(q, 8);
            if (ml == 0) {
                int row = mt * 16 + quad * 4 + r;
                redS[row * 4 + wv] = s; redQ[row * 4 + wv] = q;
            }
        }
    __syncthreads();
    if (tid < 64) {
        float S = redS[tid * 4] + redS[tid * 4 + 1] + redS[tid * 4 + 2] + redS[tid * 4 + 3];
        float Q = redQ[tid * 4] + redQ[tid * 4 + 1] + redQ[tid * 4 + 2] + redQ[tid * 4 + 3];
        float mu = S * (1.f / 256.f);
        float var = Q * (1.f / 256.f) - mu * mu;
        muA[tid] = mu; rsA[tid] = rsqrtf(var + EPSV);
    }
    __syncthreads();
    int n = m0 >> 14, y = (m0 >> 7) & 127, x0 = m0 & 127;
    int cg = tid >> 5, xi = tid & 31;
    // two half-width passes: cols [0,128) then [128,256)
#pragma unroll
    for (int half = 0; half < 2; ++half) {
        if ((wv >> 1) == half) {
#pragma unroll
            for (int mt = 0; mt < 4; ++mt)
#pragma unroll
                for (int r = 0; r < 4; ++r) {
                    int row = mt * 16 + quad * 4 + r;
                    float mu = muA[row], rs = rsA[row];
#pragma unroll
                    for (int nt = 0; nt < 4; ++nt) {
                        int col = wv * 64 + nt * 16 + ml;
                        int lc = col - half * 128;
                        olds[row * 129 + lc] = (acc[mt][nt][r] - mu) * rs * g2[col] + b2[col];
                    }
                }
        }
        __syncthreads();
        for (int cc = 0; cc < 16; ++cc) {
            int lc = cc * 8 + cg;
            int c = half * 128 + lc;
            size_t gbase = ((size_t)(n * 256 + c) * 128 + y) * 128 + x0;
#pragma unroll
            for (int xc = 0; xc < 2; ++xc) {
                int p = xc * 32 + xi;
                outp[gbase + p] = xin[gbase + p] + olds[p * 129 + lc];
            }
        }
        __syncthreads();
    }
}

extern "C" void kernel_launch(void* const* d_in, const int* in_sizes, int n_in,
                              void* d_out, int out_size, void* d_ws, size_t ws_size,
                              hipStream_t stream) {
    (void)in_sizes; (void)n_in; (void)out_size; (void)ws_size;
    const float* x1     = (const float*)d_in[0];
    const float* x2     = (const float*)d_in[1];
    const float* qk_w   = (const float*)d_in[2];
    const float* qk_g   = (const float*)d_in[3];
    const float* qk_b   = (const float*)d_in[4];
    const float* qk_m   = (const float*)d_in[5];
    const float* qk_v   = (const float*)d_in[6];
    const float* v_w    = (const float*)d_in[7];
    const float* v_g    = (const float*)d_in[8];
    const float* v_b    = (const float*)d_in[9];
    const float* v_m    = (const float*)d_in[10];
    const float* v_v    = (const float*)d_in[11];
    const float* ln1_g  = (const float*)d_in[12];
    const float* ln1_b  = (const float*)d_in[13];
    const float* ln2_g  = (const float*)d_in[14];
    const float* ln2_b  = (const float*)d_in[15];
    const float* merge_w = (const float*)d_in[16];
    const float* mlp_w1 = (const float*)d_in[17];
    const float* mlp_w2 = (const float*)d_in[18];

    float* ws      = (float*)d_ws;
    float* pooled  = ws + OFF_P;
    float* qkvbuf  = ws + OFF_Q;     // q,k,v1,v2 contiguous, 1,048,576 apart
    float* v1buf   = ws + OFF_V1;
    float* v2buf   = ws + OFF_V2;
    float* m1buf   = ws + OFF_M1;
    float* m2buf   = ws + OFF_M2;
    float* mgbuf   = ws + OFF_MG;
    ushort_t* scores16 = (ushort_t*)(ws + OFF_A); // scores bf16 -> z bf16 (stream-ordered reuse)
    ushort_t* qkb16 = (ushort_t*)(ws + OFF_P);   // q bf16 then k bf16 (pooled dead after dwbn)
    ushort_t* v2tb = (ushort_t*)(ws + OFF_V2T);  // v2 transposed bf16 (second half of dead pooled)
    ushort_t* zb16 = (ushort_t*)(ws + OFF_A);
    ushort_t* w1b  = (ushort_t*)(ws + OFF_W1B);
    ushort_t* w2b  = (ushort_t*)(ws + OFF_W2B);
    ushort_t* hid  = (ushort_t*)(ws + OFF_HID);
    float* outp    = (float*)d_out;

    hipMemsetAsync(m2buf, 0, 1048576 * sizeof(float), stream);

    pool_kernel<<<8192, 256, 0, stream>>>(x1, x2, pooled);
    lnc_kernel<<<8192, 256, 0, stream>>>(pooled, ln1_g, ln1_b);
    dwbn_kernel<<<dim3(4096, 4), 256, 0, stream>>>(pooled,
        qk_w, qk_g, qk_b, qk_m, qk_v, v_w, v_g, v_b, v_m, v_v, qkvbuf);
    // q,k (contiguous at OFF_Q..OFF_K) -> bf16 into dead pooled region
    cvt_kernel<<<8192, 256, 0, stream>>>(qkvbuf, qkb16, 2097152);
    v2t_kernel<<<1024, 256, 0, stream>>>(v2buf, v2tb);
    qk_mfma<<<dim3(8, 8, 32), 256, 0, stream>>>(qkb16, qkb16 + 1048576, scores16);
    m1_kernel<<<dim3(16, 8, 4), 256, 0, stream>>>(scores16, v2tb, m1buf);
    m2_kernel<<<dim3(32, 8, 4), 256, 0, stream>>>(scores16, v1buf, m2buf);

    // weight conversion (after m1/m2: w1b/w2b live beyond the z region)
    cvt_kernel<<<1024, 256, 0, stream>>>(mlp_w1, w1b, 262144);
    cvt_kernel<<<512, 256, 0, stream>>>(mlp_w2, w2b, 131072);

    for (int br = 0; br < 2; ++br) {
        const float* xin = br ? x2 : x1;
        const float* mm  = br ? m2buf : m1buf;
        merge_kernel<<<512, 256, 0, stream>>>(mm, merge_w, mgbuf);
        zbuild_kernel<<<2048, 256, 0, stream>>>(xin, mgbuf, zb16);
        mfma_gemm<<<dim3(512, 4), 256, 0, stream>>>(zb16, w1b, nullptr, hid, 512, 1);
        gemm2_ln<<<1024, 256, 0, stream>>>(hid, w2b, xin, ln2_g, ln2_b,
                                           outp + (size_t)br * 16777216);
    }
}

// Round 4
// 685.469 us; speedup vs baseline: 1.3464x; 1.1195x over previous
//
#include <hip/hip_runtime.h>
#include <hip/hip_bf16.h>

// Problem constants
#define NB 4
#define NC 256
#define NH_ 8
#define LPOOL 1024          // 32*32
constexpr float EPSV = 1e-5f;

typedef unsigned short ushort_t;
typedef __attribute__((ext_vector_type(8))) short bf16x8;
typedef __attribute__((ext_vector_type(4))) float f32x4;

// workspace offsets (in floats)
#define OFF_P   0u                  // pooled/normed: 2*4*256*1024 = 2,097,152 (reused for bf16 q/k + v2t after dwbn)
#define OFF_V2T 1048576u            // v2 transposed bf16 [n][c][s]: 1,048,576 ushorts = 524,288 float slots
#define OFF_Q   2097152u            // 1,048,576 each
#define OFF_K   3145728u
#define OFF_V1  4194304u            // v1 f32; dead after m2 -> mb16 (bf16 of m2) lives here
#define OFF_V2  5242880u
#define OFF_M1  6291456u            // m1 bf16 (written directly by m1_kernel)
#define OFF_M2  7340032u            // m2 f32 (atomicAdd)
#define OFF_MG  8388608u            // mm1 bf16 [4096][512] = 2M ushorts = 1M float slots
#define OFF_A   9437184u            // RegionA: scores bf16 (33.5M ushorts) -> hid bf16 (33.5M ushorts)
#define OFF_W1B 26214400u           // bf16 w1: 262144 ushorts = 131072 float slots
#define OFF_W2B 26345472u           // bf16 w2: 131072 ushorts =  65536 float slots
#define OFF_WCB 26411008u           // bf16 Wc = W1b@merge_w: 512*256 ushorts = 65536 float slots

__device__ __forceinline__ float bf16_to_f(unsigned short u) {
    union { unsigned int ui; float f; } t; t.ui = ((unsigned int)u) << 16; return t.f;
}
__device__ __forceinline__ unsigned short f_to_bf16(float f) {
    union { float f; unsigned int u; } t; t.f = f;
    unsigned int u = t.u;
    u += 0x7fffu + ((u >> 16) & 1u);
    return (unsigned short)(u >> 16);
}

// ---------------- maxpool 4x4 (both branches) ----------------
__global__ __launch_bounds__(256) void pool_kernel(const float* __restrict__ x1,
                                                   const float* __restrict__ x2,
                                                   float* __restrict__ pooled) {
    int idx = blockIdx.x * 256 + threadIdx.x;           // 2^21 total
    int j = idx & 31, i = (idx >> 5) & 31, c = (idx >> 10) & 255, n = (idx >> 18) & 3, br = idx >> 20;
    const float* xp = br ? x2 : x1;
    const float* base = xp + (((size_t)(n * 256 + c) * 128 + i * 4) * 128 + j * 4);
    float m = -3.4e38f;
#pragma unroll
    for (int r = 0; r < 4; ++r) {
        float4 v = *(const float4*)(base + r * 128);
        m = fmaxf(m, fmaxf(fmaxf(v.x, v.y), fmaxf(v.z, v.w)));
    }
    pooled[(size_t)br * 1048576 + (size_t)(n * 256 + c) * 1024 + i * 32 + j] = m;
}

// ---------------- LayerNorm over channel dim, in place ----------------
__global__ __launch_bounds__(256) void lnc_kernel(float* __restrict__ p,
                                                  const float* __restrict__ g,
                                                  const float* __restrict__ b) {
    int bid = blockIdx.x;                                // (br,n,l)
    int l = bid & 1023, n = (bid >> 10) & 3, br = bid >> 12;
    int c = threadIdx.x;
    size_t idx = (size_t)br * 1048576 + (size_t)(n * 256 + c) * 1024 + l;
    float v = p[idx];
    __shared__ float red[256];
    red[c] = v; __syncthreads();
    for (int off = 128; off > 0; off >>= 1) { if (c < off) red[c] += red[c + off]; __syncthreads(); }
    float mean = red[0] / 256.f;
    __syncthreads();
    float d = v - mean;
    red[c] = d * d; __syncthreads();
    for (int off = 128; off > 0; off >>= 1) { if (c < off) red[c] += red[c + off]; __syncthreads(); }
    float var = red[0] / 256.f;
    float rstd = rsqrtf(var + EPSV);
    p[idx] = (v - mean) * rstd * g[c] + b[c];
}

// ---------------- depthwise 3x3 conv + BN; writes heads layout [n][l][c] ----------------
__global__ __launch_bounds__(256) void dwbn_kernel(const float* __restrict__ p,
    const float* __restrict__ qkw, const float* __restrict__ qkg, const float* __restrict__ qkb,
    const float* __restrict__ qkm, const float* __restrict__ qkv,
    const float* __restrict__ vw, const float* __restrict__ vg, const float* __restrict__ vb,
    const float* __restrict__ vm, const float* __restrict__ vv,
    float* __restrict__ qkvbuf) {
    int which = blockIdx.y;                        // 0:q(p1,qk) 1:k(p2,qk) 2:v1(p1,v) 3:v2(p2,v)
    int flat = blockIdx.x * 256 + threadIdx.x;     // 2^20
    int l = flat & 1023, c = (flat >> 10) & 255, n = flat >> 18;
    int br = which & 1;
    const float* w  = (which < 2) ? qkw : vw;
    const float* g  = (which < 2) ? qkg : vg;
    const float* bb = (which < 2) ? qkb : vb;
    const float* rm = (which < 2) ? qkm : vm;
    const float* rv = (which < 2) ? qkv : vv;
    int i = l >> 5, j = l & 31;
    const float* pin = p + (size_t)br * 1048576 + (size_t)(n * 256 + c) * 1024;
    float acc = 0.f;
#pragma unroll
    for (int ky = -1; ky <= 1; ++ky) {
        int yy = i + ky;
        if ((unsigned)yy < 32u) {
#pragma unroll
            for (int kx = -1; kx <= 1; ++kx) {
                int xx = j + kx;
                if ((unsigned)xx < 32u)
                    acc += pin[yy * 32 + xx] * w[c * 9 + (ky + 1) * 3 + (kx + 1)];
            }
        }
    }
    float sc = g[c] * rsqrtf(rv[c] + EPSV);
    qkvbuf[(size_t)which * 1048576 + (size_t)(n * 1024 + l) * 256 + c] = sc * (acc - rm[c]) + bb[c];
}

// ---------------- fp32 -> bf16 conversion ----------------
__global__ __launch_bounds__(256) void cvt_kernel(const float* __restrict__ in,
                                                  ushort_t* __restrict__ out, int n) {
    int i = blockIdx.x * 256 + threadIdx.x;
    if (i < n) out[i] = f_to_bf16(in[i]);
}

// ---------------- Wc[512][256] = W1[:, 256:512] @ merge_w  (bf16 out) ----------------
__global__ __launch_bounds__(256) void wc_kernel(const float* __restrict__ w1,
                                                 const float* __restrict__ mw,
                                                 ushort_t* __restrict__ wcb) {
    int r = blockIdx.x, t = threadIdx.x;
    __shared__ float wrow[256];
    wrow[t] = w1[(size_t)r * 512 + 256 + t];
    __syncthreads();
    float acc = 0.f;
    for (int c = 0; c < 256; ++c) acc += wrow[c] * mw[(size_t)c * 256 + t];
    wcb[(size_t)r * 256 + t] = f_to_bf16(acc);
}

// ---------------- v2 [n][s][c] f32 -> v2t [n][c][s] bf16 (32x32 LDS tile transpose) ----------------
__global__ __launch_bounds__(256) void v2t_kernel(const float* __restrict__ v,
                                                  ushort_t* __restrict__ vt) {
    int bid = blockIdx.x;
    int sb = bid & 31, cb = (bid >> 5) & 7, n = bid >> 8;
    int tid = threadIdx.x;
    __shared__ float t[32][33];
    int ci = tid & 31, sg = tid >> 5;
#pragma unroll
    for (int p = 0; p < 4; ++p) {
        int s = sb * 32 + p * 8 + sg;
        t[p * 8 + sg][ci] = v[(size_t)(n * 1024 + s) * 256 + cb * 32 + ci];
    }
    __syncthreads();
    int si = tid & 31, cg = tid >> 5;
#pragma unroll
    for (int p = 0; p < 4; ++p) {
        int c = cb * 32 + p * 8 + cg;
        vt[(size_t)(n * 256 + c) * 1024 + sb * 32 + si] = f_to_bf16(t[si][p * 8 + cg]);
    }
}

// ---------------- scores[n][h][l][s] (bf16) = t * Q_h K_h^T via MFMA bf16 ----------------
__global__ __launch_bounds__(256) void qk_mfma(const ushort_t* __restrict__ qb,
                                               const ushort_t* __restrict__ kb,
                                               ushort_t* __restrict__ scores) {
    int lt = blockIdx.x, st = blockIdx.y;
    int nh = blockIdx.z; int n = nh >> 3, h = nh & 7;
    int l0 = lt * 128, s0 = st * 128;
    __shared__ ushort_t Qs[128 * 32];
    __shared__ ushort_t Ks[128 * 32];
    int tid = threadIdx.x, lane = tid & 63, wv = tid >> 6;
    int wm = wv >> 1, wn = wv & 1;
    int ml = lane & 15, quad = lane >> 4;
#pragma unroll
    for (int c = 0; c < 2; ++c) {
        int g = c * 256 + tid;
        int row = g >> 2, seg = g & 3;
        const ushort_t* ga = qb + (size_t)(n * 1024 + l0 + row) * 256 + h * 32 + seg * 8;
        __builtin_amdgcn_global_load_lds((const __attribute__((address_space(1))) void*)ga,
                                         (__attribute__((address_space(3))) void*)&Qs[row * 32 + seg * 8], 16, 0, 0);
        const ushort_t* gk = kb + (size_t)(n * 1024 + s0 + row) * 256 + h * 32 + seg * 8;
        __builtin_amdgcn_global_load_lds((const __attribute__((address_space(1))) void*)gk,
                                         (__attribute__((address_space(3))) void*)&Ks[row * 32 + seg * 8], 16, 0, 0);
    }
    __syncthreads();
    f32x4 acc[4][4];
#pragma unroll
    for (int i = 0; i < 4; ++i)
#pragma unroll
        for (int j = 0; j < 4; ++j) acc[i][j] = (f32x4)(0.f);
    bf16x8 af[4], bfr[4];
#pragma unroll
    for (int mt = 0; mt < 4; ++mt)
        af[mt] = *(const bf16x8*)&Qs[(wm * 64 + mt * 16 + ml) * 32 + quad * 8];
#pragma unroll
    for (int nt = 0; nt < 4; ++nt)
        bfr[nt] = *(const bf16x8*)&Ks[(wn * 64 + nt * 16 + ml) * 32 + quad * 8];
#pragma unroll
    for (int mt = 0; mt < 4; ++mt)
#pragma unroll
        for (int nt = 0; nt < 4; ++nt)
            acc[mt][nt] = __builtin_amdgcn_mfma_f32_16x16x32_bf16(af[mt], bfr[nt], acc[mt][nt], 0, 0, 0);
    const float tsc = 0.17677669529663687f;   // 1/sqrt(32)
    ushort_t* sb = scores + (size_t)nh * 1024 * 1024;
#pragma unroll
    for (int mt = 0; mt < 4; ++mt)
#pragma unroll
        for (int nt = 0; nt < 4; ++nt) {
            int col = s0 + wn * 64 + nt * 16 + ml;
#pragma unroll
            for (int r = 0; r < 4; ++r) {
                int row = l0 + wm * 64 + mt * 16 + quad * 4 + r;
                unsigned short b = f_to_bf16(tsc * acc[mt][nt][r]);
                int partner = __shfl_xor((int)b, 1);
                if (!(ml & 1)) {
                    unsigned int pk = (unsigned int)b | ((unsigned int)partner << 16);
                    *(unsigned int*)&sb[(size_t)row * 1024 + col] = pk;
                }
            }
        }
}

// ---------------- m1[n,l,h,d] = softmax_s(sc) @ v2 -> bf16 out ----------------
__global__ __launch_bounds__(256) void m1_kernel(const ushort_t* __restrict__ scores,
                                                 const ushort_t* __restrict__ v2t,
                                                 ushort_t* __restrict__ m1out) {
    int lt = blockIdx.x, h = blockIdx.y, n = blockIdx.z;
    int tid = threadIdx.x, lane = tid & 63, wv = tid >> 6;
    int ml = lane & 15, quad = lane >> 4;
    int l0 = lt * 64 + wv * 16;
    const ushort_t* arow = scores + (size_t)((n * 8 + h) * 1024 + l0 + ml) * 1024 + quad * 8;
    const ushort_t* vb = v2t + (size_t)(n * 256 + h * 32) * 1024;
    const ushort_t* vrow0 = vb + (size_t)ml * 1024 + quad * 8;
    const ushort_t* vrow1 = vb + (size_t)(ml + 16) * 1024 + quad * 8;
    f32x4 acc0 = (f32x4)(0.f), acc1 = (f32x4)(0.f);
    float rsum = 0.f;
#pragma unroll 4
    for (int s0 = 0; s0 < 1024; s0 += 32) {
        bf16x8 sv = *(const bf16x8*)(arow + s0);
        float e0 = __expf(bf16_to_f((ushort_t)sv[0]));
        float e1 = __expf(bf16_to_f((ushort_t)sv[1]));
        float e2 = __expf(bf16_to_f((ushort_t)sv[2]));
        float e3 = __expf(bf16_to_f((ushort_t)sv[3]));
        float e4 = __expf(bf16_to_f((ushort_t)sv[4]));
        float e5 = __expf(bf16_to_f((ushort_t)sv[5]));
        float e6 = __expf(bf16_to_f((ushort_t)sv[6]));
        float e7 = __expf(bf16_to_f((ushort_t)sv[7]));
        rsum += ((e0 + e1) + (e2 + e3)) + ((e4 + e5) + (e6 + e7));
        bf16x8 af;
        af[0] = (short)f_to_bf16(e0); af[1] = (short)f_to_bf16(e1);
        af[2] = (short)f_to_bf16(e2); af[3] = (short)f_to_bf16(e3);
        af[4] = (short)f_to_bf16(e4); af[5] = (short)f_to_bf16(e5);
        af[6] = (short)f_to_bf16(e6); af[7] = (short)f_to_bf16(e7);
        bf16x8 b0 = *(const bf16x8*)(vrow0 + s0);
        bf16x8 b1 = *(const bf16x8*)(vrow1 + s0);
        acc0 = __builtin_amdgcn_mfma_f32_16x16x32_bf16(af, b0, acc0, 0, 0, 0);
        acc1 = __builtin_amdgcn_mfma_f32_16x16x32_bf16(af, b1, acc1, 0, 0, 0);
    }
    rsum += __shfl_xor(rsum, 16);
    rsum += __shfl_xor(rsum, 32);
#pragma unroll
    for (int r = 0; r < 4; ++r) {
        int row = quad * 4 + r;
        float inv = 1.f / __shfl(rsum, row);
        size_t ob = (size_t)(n * 1024 + l0 + row) * 256 + h * 32;
        m1out[ob + ml] = f_to_bf16(acc0[r] * inv);
        m1out[ob + 16 + ml] = f_to_bf16(acc1[r] * inv);
    }
}

// ---------------- m2[n,s,h,d] = sum_l softmax_h(sc)[l,s,h] * v1[l, h*32+d] ----------------
__global__ __launch_bounds__(256) void m2_kernel(const ushort_t* __restrict__ scores,
                                                 const float* __restrict__ v1,
                                                 float* __restrict__ m2out) {
    int st = blockIdx.x;       // 32 tiles of 32 s
    int lc = blockIdx.y;       // 8 chunks of 128 l
    int n  = blockIdx.z;
    int s0 = st * 32, tid = threadIdx.x;
    __shared__ float wls[8][8][32];   // [l_sub][h][s]
    float acc[32];
#pragma unroll
    for (int i = 0; i < 32; ++i) acc[i] = 0.f;
    int lA = tid >> 5, siA = tid & 31;
    int hB = tid >> 5;
    const ushort_t* sbase = scores + (size_t)n * 8 * 1024 * 1024;
    int lend = lc * 128 + 128;
    for (int lb = lc * 128; lb < lend; lb += 8) {
        int l = lb + lA;
        float e[8];
        float mx = -3.4e38f;
#pragma unroll
        for (int h = 0; h < 8; ++h) {
            e[h] = bf16_to_f(sbase[((size_t)h * 1024 + l) * 1024 + s0 + siA]);
            mx = fmaxf(mx, e[h]);
        }
        float sum = 0.f;
#pragma unroll
        for (int h = 0; h < 8; ++h) { e[h] = expf(e[h] - mx); sum += e[h]; }
        float inv = 1.f / sum;
#pragma unroll
        for (int h = 0; h < 8; ++h) wls[lA][h][siA] = e[h] * inv;
        __syncthreads();
#pragma unroll
        for (int ls = 0; ls < 8; ++ls) {
            float v1v = v1[(size_t)(n * 1024 + lb + ls) * 256 + tid];
#pragma unroll
            for (int s4 = 0; s4 < 8; ++s4) {
                float4 w4 = *(const float4*)&wls[ls][hB][s4 * 4];
                acc[s4 * 4]     += w4.x * v1v;
                acc[s4 * 4 + 1] += w4.y * v1v;
                acc[s4 * 4 + 2] += w4.z * v1v;
                acc[s4 * 4 + 3] += w4.w * v1v;
            }
        }
        __syncthreads();
    }
#pragma unroll
    for (int ss = 0; ss < 32; ++ss)
        atomicAdd(&m2out[(size_t)(n * 1024 + s0 + ss) * 256 + tid], acc[ss]);
}

// ---------------- MFMA bf16 GEMM (runtime K): C[M,N] = act(A[M,K] @ B[N,K]^T) ----------------
__global__ __launch_bounds__(256) void mfma_gemm(const ushort_t* __restrict__ A,
                                                 const ushort_t* __restrict__ B,
                                                 float* __restrict__ Of,
                                                 ushort_t* __restrict__ Oh,
                                                 int N, int relu, int K) {
    int m0 = blockIdx.x * 128, n0 = blockIdx.y * 128;
    int tid = threadIdx.x;
    __shared__ ushort_t Al[128 * 32];
    __shared__ ushort_t Bl[128 * 32];
    int lane = tid & 63;
    int wv = tid >> 6;
    int wm = wv >> 1, wn = wv & 1;
    int ml = lane & 15, quad = lane >> 4;
    f32x4 acc[4][4];
#pragma unroll
    for (int i = 0; i < 4; ++i)
#pragma unroll
        for (int j = 0; j < 4; ++j) acc[i][j] = (f32x4)(0.f);

    for (int k0 = 0; k0 < K; k0 += 32) {
#pragma unroll
        for (int c = 0; c < 2; ++c) {
            int g = c * 256 + tid;
            int row = g >> 2, seg = g & 3;
            const ushort_t* ga = A + (size_t)(m0 + row) * K + k0 + seg * 8;
            __builtin_amdgcn_global_load_lds((const __attribute__((address_space(1))) void*)ga,
                                             (__attribute__((address_space(3))) void*)&Al[g * 8], 16, 0, 0);
            const ushort_t* gb = B + (size_t)(n0 + row) * K + k0 + seg * 8;
            __builtin_amdgcn_global_load_lds((const __attribute__((address_space(1))) void*)gb,
                                             (__attribute__((address_space(3))) void*)&Bl[g * 8], 16, 0, 0);
        }
        __syncthreads();
        bf16x8 af[4], bfr[4];
#pragma unroll
        for (int mt = 0; mt < 4; ++mt)
            af[mt] = *(const bf16x8*)&Al[(wm * 64 + mt * 16 + ml) * 32 + quad * 8];
#pragma unroll
        for (int nt = 0; nt < 4; ++nt)
            bfr[nt] = *(const bf16x8*)&Bl[(wn * 64 + nt * 16 + ml) * 32 + quad * 8];
#pragma unroll
        for (int mt = 0; mt < 4; ++mt)
#pragma unroll
            for (int nt = 0; nt < 4; ++nt)
                acc[mt][nt] = __builtin_amdgcn_mfma_f32_16x16x32_bf16(af[mt], bfr[nt], acc[mt][nt], 0, 0, 0);
        __syncthreads();
    }
#pragma unroll
    for (int mt = 0; mt < 4; ++mt) {
#pragma unroll
        for (int nt = 0; nt < 4; ++nt) {
            int col = n0 + wn * 64 + nt * 16 + ml;
#pragma unroll
            for (int r = 0; r < 4; ++r) {
                int row = m0 + wm * 64 + mt * 16 + quad * 4 + r;
                float v = acc[mt][nt][r];
                if (relu) v = fmaxf(v, 0.f);
                if (Oh) Oh[(size_t)row * N + col] = f_to_bf16(v);
                else    Of[(size_t)row * N + col] = v;
            }
        }
    }
}

// ---------------- fused GEMM1: hid[pix][512] = relu(x_nhwc @ W1a^T + up(mm1)) ----------------
// Block: 64 pixels (half image row) x 256 out-cols (n-tile), K=256.
// A (x) is transposed NCHW->[pix][c] in-kernel: coalesced f32 reads -> padded t32 tile ->
// XOR-swizzled bf16 A-LDS (T2: same swizzle write+read -> conflict-free ds_read_b128).
// B (W1 rows, k<256) staged via global_load_lds as in gemm2_ln. up(mm1) added in epilogue.
__global__ __launch_bounds__(256) void gemm1_fused(const float* __restrict__ x,
                                                   const ushort_t* __restrict__ W1,
                                                   const ushort_t* __restrict__ mm1,
                                                   ushort_t* __restrict__ hid) {
    __shared__ char smem[49152];
    ushort_t* Abf = (ushort_t*)smem;             // [64][256] bf16 swizzled = 32KB
    ushort_t* Bl  = (ushort_t*)(smem + 32768);   // [256][32] bf16 = 16KB
    float* t32    = (float*)(smem + 32768);      // [32][68] f32 = 8704B (overlaps Bl, prologue only)
    int m0 = blockIdx.x * 64;
    int n = m0 >> 14, y = (m0 >> 7) & 127, x0 = m0 & 127;
    int n0 = blockIdx.y * 256;
    int tid = threadIdx.x, lane = tid & 63;
    int wv = tid >> 6, ml = lane & 15, quad = lane >> 4;

    // ---- prologue: transpose x[n][0..255][y][x0..x0+63] -> Abf[pix][c]
    const float* xrow = x + ((size_t)(n * 256) * 128 + y) * 128 + x0;
    for (int cb = 0; cb < 256; cb += 32) {
        __syncthreads();    // protect t32 (and Bl overlap on first iter: none yet)
        {
            int l16 = tid & 15, cl = tid >> 4;   // 16 x-quads x 16 c-rows
#pragma unroll
            for (int pp = 0; pp < 2; ++pp) {
                int c = cb + pp * 16 + cl;
                float4 v = *(const float4*)(xrow + (size_t)c * 16384 + l16 * 4);
                *(float4*)&t32[(pp * 16 + cl) * 68 + l16 * 4] = v;
            }
        }
        __syncthreads();
        {
            int clw = tid & 31, pg = tid >> 5;   // lanes sweep c (contiguous writes)
#pragma unroll
            for (int k = 0; k < 8; ++k) {
                int pix = pg * 8 + k;
                float v = t32[clw * 68 + pix];
                unsigned byte = ((unsigned)(pix * 256 + cb + clw) * 2u) ^ ((unsigned)(pix & 7) << 4);
                *(ushort_t*)(smem + byte) = f_to_bf16(v);
            }
        }
    }
    __syncthreads();

    // ---- K-loop: 8 steps of 32
    f32x4 acc[4][4];
#pragma unroll
    for (int i = 0; i < 4; ++i)
#pragma unroll
        for (int j = 0; j < 4; ++j) acc[i][j] = (f32x4)(0.f);
    for (int k0 = 0; k0 < 256; k0 += 32) {
#pragma unroll
        for (int c = 0; c < 4; ++c) {   // stage B: 256 rows x 32 k
            int g = c * 256 + tid;
            int row = g >> 2, seg = g & 3;
            const ushort_t* gb = W1 + (size_t)(n0 + row) * 512 + k0 + seg * 8;
            __builtin_amdgcn_global_load_lds((const __attribute__((address_space(1))) void*)gb,
                                             (__attribute__((address_space(3))) void*)&Bl[g * 8], 16, 0, 0);
        }
        __syncthreads();
        bf16x8 af[4], bfr[4];
#pragma unroll
        for (int mt = 0; mt < 4; ++mt) {
            int pix = mt * 16 + ml;
            unsigned byte = ((unsigned)(pix * 256 + k0 + quad * 8) * 2u) ^ ((unsigned)(pix & 7) << 4);
            af[mt] = *(const bf16x8*)(smem + byte);
        }
#pragma unroll
        for (int nt = 0; nt < 4; ++nt)
            bfr[nt] = *(const bf16x8*)&Bl[(wv * 64 + nt * 16 + ml) * 32 + quad * 8];
#pragma unroll
        for (int mt = 0; mt < 4; ++mt)
#pragma unroll
            for (int nt = 0; nt < 4; ++nt)
                acc[mt][nt] = __builtin_amdgcn_mfma_f32_16x16x32_bf16(af[mt], bfr[nt], acc[mt][nt], 0, 0, 0);
        __syncthreads();
    }

    // ---- epilogue: add bilinear-up(mm1), relu, write hid bf16
    float iy = y * 0.25f - 0.375f;
    int y0i = (int)floorf(iy);
    float fy = iy - (float)y0i;
    int y0c = max(y0i, 0), y1c = min(y0i + 1, 31);
    const ushort_t* mb0 = mm1 + (size_t)(n * 1024 + y0c * 32) * 512;
    const ushort_t* mb1 = mm1 + (size_t)(n * 1024 + y1c * 32) * 512;
#pragma unroll
    for (int mt = 0; mt < 4; ++mt)
#pragma unroll
        for (int r = 0; r < 4; ++r) {
            int p = mt * 16 + quad * 4 + r;
            int xx = x0 + p;
            float ix = xx * 0.25f - 0.375f;
            int x0i = (int)floorf(ix);
            float fx = ix - (float)x0i;
            int xc0 = max(x0i, 0), xc1 = min(x0i + 1, 31);
#pragma unroll
            for (int nt = 0; nt < 4; ++nt) {
                int col = n0 + wv * 64 + nt * 16 + ml;
                float v00 = bf16_to_f(mb0[(size_t)xc0 * 512 + col]);
                float v01 = bf16_to_f(mb0[(size_t)xc1 * 512 + col]);
                float v10 = bf16_to_f(mb1[(size_t)xc0 * 512 + col]);
                float v11 = bf16_to_f(mb1[(size_t)xc1 * 512 + col]);
                float up = (1.f - fy) * ((1.f - fx) * v00 + fx * v01)
                         + fy * ((1.f - fx) * v10 + fx * v11);
                float v = fmaxf(acc[mt][nt][r] + up, 0.f);
                hid[(size_t)(m0 + p) * 512 + col] = f_to_bf16(v);
            }
        }
}

// ---------------- fused GEMM2 + LN + residual + NCHW write ----------------
__global__ __launch_bounds__(256) void gemm2_ln(const ushort_t* __restrict__ hid,
                                                const ushort_t* __restrict__ W2,
                                                const float* __restrict__ xin,
                                                const float* __restrict__ g2,
                                                const float* __restrict__ b2,
                                                float* __restrict__ outp) {
    __shared__ char smem[35584];
    ushort_t* Al = (ushort_t*)smem;              // [64][32] bf16 = 4KB
    ushort_t* Bl = (ushort_t*)(smem + 4096);     // [256][32] bf16 = 16KB
    int m0 = blockIdx.x * 64;
    int tid = threadIdx.x, lane = tid & 63, wv = tid >> 6;
    int ml = lane & 15, quad = lane >> 4;
    f32x4 acc[4][4];
#pragma unroll
    for (int i = 0; i < 4; ++i)
#pragma unroll
        for (int j = 0; j < 4; ++j) acc[i][j] = (f32x4)(0.f);

    for (int k0 = 0; k0 < 512; k0 += 32) {
        {
            int row = tid >> 2, seg = tid & 3;
            const ushort_t* ga = hid + (size_t)(m0 + row) * 512 + k0 + seg * 8;
            __builtin_amdgcn_global_load_lds((const __attribute__((address_space(1))) void*)ga,
                                             (__attribute__((address_space(3))) void*)&Al[tid * 8], 16, 0, 0);
        }
#pragma unroll
        for (int c = 0; c < 4; ++c) {
            int g = c * 256 + tid;
            int row = g >> 2, seg = g & 3;
            const ushort_t* gb = W2 + (size_t)row * 512 + k0 + seg * 8;
            __builtin_amdgcn_global_load_lds((const __attribute__((address_space(1))) void*)gb,
                                             (__attribute__((address_space(3))) void*)&Bl[g * 8], 16, 0, 0);
        }
        __syncthreads();
        bf16x8 af[4], bfr[4];
#pragma unroll
        for (int mt = 0; mt < 4; ++mt)
            af[mt] = *(const bf16x8*)&Al[(mt * 16 + ml) * 32 + quad * 8];
#pragma unroll
        for (int nt = 0; nt < 4; ++nt)
            bfr[nt] = *(const bf16x8*)&Bl[(wv * 64 + nt * 16 + ml) * 32 + quad * 8];
#pragma unroll
        for (int mt = 0; mt < 4; ++mt)
#pragma unroll
            for (int nt = 0; nt < 4; ++nt)
                acc[mt][nt] = __builtin_amdgcn_mfma_f32_16x16x32_bf16(af[mt], bfr[nt], acc[mt][nt], 0, 0, 0);
        __syncthreads();
    }
    float* redS = (float*)smem;            // [64][4]
    float* redQ = (float*)(smem + 1024);   // [64][4]
    float* muA  = (float*)(smem + 2048);   // [64]
    float* rsA  = (float*)(smem + 2304);   // [64]
    float* olds = (float*)(smem + 2560);   // [64][129]
#pragma unroll
    for (int mt = 0; mt < 4; ++mt)
#pragma unroll
        for (int r = 0; r < 4; ++r) {
            float s = 0.f, q = 0.f;
#pragma unroll
            for (int nt = 0; nt < 4; ++nt) { float v = acc[mt][nt][r]; s += v; q += v * v; }
            s += __shfl_xor(s, 1); s += __shfl_xor(s, 2); s += __shfl_xor(s, 4); s += __shfl_xor(s, 8);
            q += __shfl_xor(q, 1); q += __shfl_xor(q, 2); q += __shfl_xor(q, 4); q += __shfl_xor(q, 8);
            if (ml == 0) {
                int row = mt * 16 + quad * 4 + r;
                redS[row * 4 + wv] = s; redQ[row * 4 + wv] = q;
            }
        }
    __syncthreads();
    if (tid < 64) {
        float S = redS[tid * 4] + redS[tid * 4 + 1] + redS[tid * 4 + 2] + redS[tid * 4 + 3];
        float Q = redQ[tid * 4] + redQ[tid * 4 + 1] + redQ[tid * 4 + 2] + redQ[tid * 4 + 3];
        float mu = S * (1.f / 256.f);
        float var = Q * (1.f / 256.f) - mu * mu;
        muA[tid] = mu; rsA[tid] = rsqrtf(var + EPSV);
    }
    __syncthreads();
    int n = m0 >> 14, y = (m0 >> 7) & 127, x0 = m0 & 127;
    int cg = tid >> 5, xi = tid & 31;
#pragma unroll
    for (int half = 0; half < 2; ++half) {
        if ((wv >> 1) == half) {
#pragma unroll
            for (int mt = 0; mt < 4; ++mt)
#pragma unroll
                for (int r = 0; r < 4; ++r) {
                    int row = mt * 16 + quad * 4 + r;
                    float mu = muA[row], rs = rsA[row];
#pragma unroll
                    for (int nt = 0; nt < 4; ++nt) {
                        int col = wv * 64 + nt * 16 + ml;
                        int lc = col - half * 128;
                        olds[row * 129 + lc] = (acc[mt][nt][r] - mu) * rs * g2[col] + b2[col];
                    }
                }
        }
        __syncthreads();
        for (int cc = 0; cc < 16; ++cc) {
            int lc = cc * 8 + cg;
            int c = half * 128 + lc;
            size_t gbase = ((size_t)(n * 256 + c) * 128 + y) * 128 + x0;
#pragma unroll
            for (int xc = 0; xc < 2; ++xc) {
                int p = xc * 32 + xi;
                outp[gbase + p] = xin[gbase + p] + olds[p * 129 + lc];
            }
        }
        __syncthreads();
    }
}

extern "C" void kernel_launch(void* const* d_in, const int* in_sizes, int n_in,
                              void* d_out, int out_size, void* d_ws, size_t ws_size,
                              hipStream_t stream) {
    (void)in_sizes; (void)n_in; (void)out_size; (void)ws_size;
    const float* x1     = (const float*)d_in[0];
    const float* x2     = (const float*)d_in[1];
    const float* qk_w   = (const float*)d_in[2];
    const float* qk_g   = (const float*)d_in[3];
    const float* qk_b   = (const float*)d_in[4];
    const float* qk_m   = (const float*)d_in[5];
    const float* qk_v   = (const float*)d_in[6];
    const float* v_w    = (const float*)d_in[7];
    const float* v_g    = (const float*)d_in[8];
    const float* v_b    = (const float*)d_in[9];
    const float* v_m    = (const float*)d_in[10];
    const float* v_v    = (const float*)d_in[11];
    const float* ln1_g  = (const float*)d_in[12];
    const float* ln1_b  = (const float*)d_in[13];
    const float* ln2_g  = (const float*)d_in[14];
    const float* ln2_b  = (const float*)d_in[15];
    const float* merge_w = (const float*)d_in[16];
    const float* mlp_w1 = (const float*)d_in[17];
    const float* mlp_w2 = (const float*)d_in[18];

    float* ws      = (float*)d_ws;
    float* pooled  = ws + OFF_P;
    float* qkvbuf  = ws + OFF_Q;     // q,k,v1,v2 contiguous, 1,048,576 apart
    float* v1buf   = ws + OFF_V1;
    float* v2buf   = ws + OFF_V2;
    float* m2buf   = ws + OFF_M2;
    ushort_t* m1b16 = (ushort_t*)(ws + OFF_M1);   // m1 bf16, written directly
    ushort_t* mb16  = (ushort_t*)(ws + OFF_V1);   // bf16 of m2 (v1 dead after m2)
    ushort_t* mm1b  = (ushort_t*)(ws + OFF_MG);   // mm1 bf16 [4096][512]
    ushort_t* scores16 = (ushort_t*)(ws + OFF_A); // scores bf16 -> hid bf16 (stream-ordered reuse)
    ushort_t* qkb16 = (ushort_t*)(ws + OFF_P);
    ushort_t* v2tb = (ushort_t*)(ws + OFF_V2T);
    ushort_t* hid  = (ushort_t*)(ws + OFF_A);
    ushort_t* w1b  = (ushort_t*)(ws + OFF_W1B);
    ushort_t* w2b  = (ushort_t*)(ws + OFF_W2B);
    ushort_t* wcb  = (ushort_t*)(ws + OFF_WCB);
    float* outp    = (float*)d_out;

    hipMemsetAsync(m2buf, 0, 1048576 * sizeof(float), stream);

    wc_kernel<<<512, 256, 0, stream>>>(mlp_w1, merge_w, wcb);
    pool_kernel<<<8192, 256, 0, stream>>>(x1, x2, pooled);
    lnc_kernel<<<8192, 256, 0, stream>>>(pooled, ln1_g, ln1_b);
    dwbn_kernel<<<dim3(4096, 4), 256, 0, stream>>>(pooled,
        qk_w, qk_g, qk_b, qk_m, qk_v, v_w, v_g, v_b, v_m, v_v, qkvbuf);
    cvt_kernel<<<8192, 256, 0, stream>>>(qkvbuf, qkb16, 2097152);
    v2t_kernel<<<1024, 256, 0, stream>>>(v2buf, v2tb);
    qk_mfma<<<dim3(8, 8, 32), 256, 0, stream>>>(qkb16, qkb16 + 1048576, scores16);
    m1_kernel<<<dim3(16, 8, 4), 256, 0, stream>>>(scores16, v2tb, m1b16);
    m2_kernel<<<dim3(32, 8, 4), 256, 0, stream>>>(scores16, v1buf, m2buf);

    cvt_kernel<<<1024, 256, 0, stream>>>(mlp_w1, w1b, 262144);
    cvt_kernel<<<512, 256, 0, stream>>>(mlp_w2, w2b, 131072);

    for (int br = 0; br < 2; ++br) {
        const float* xin = br ? x2 : x1;
        const ushort_t* mmb;
        if (br == 0) {
            mmb = m1b16;
        } else {
            cvt_kernel<<<4096, 256, 0, stream>>>(m2buf, mb16, 1048576);
            mmb = mb16;
        }
        // mm1[4096][512] = m @ Wc^T  (M=4096, N=512, K=256)
        mfma_gemm<<<dim3(32, 4), 256, 0, stream>>>(mmb, wcb, nullptr, mm1b, 512, 0, 256);
        gemm1_fused<<<dim3(1024, 2), 256, 0, stream>>>(xin, w1b, mm1b, hid);
        gemm2_ln<<<1024, 256, 0, stream>>>(hid, w2b, xin, ln2_g, ln2_b,
                                           outp + (size_t)br * 16777216);
    }
}

// Round 5
// 661.700 us; speedup vs baseline: 1.3948x; 1.0359x over previous
//
#include <hip/hip_runtime.h>
#include <hip/hip_bf16.h>

// Problem constants
#define NB 4
#define NC 256
#define NH_ 8
#define LPOOL 1024          // 32*32
constexpr float EPSV = 1e-5f;

typedef unsigned short ushort_t;
typedef __attribute__((ext_vector_type(8))) short bf16x8;
typedef __attribute__((ext_vector_type(4))) float f32x4;

// workspace offsets (in floats)
#define OFF_P   0u                  // pooled/normed f32: 2*4*256*1024 = 2,097,152
#define OFF_Q   2097152u            // q,k bf16 (2M ushorts = 1M float slots) -- old f32 q region reused
#define OFF_K   3145728u            // v2t bf16 [n][c][s] (1M ushorts = 512K float slots) -- old f32 k region
#define OFF_V1  4194304u            // v1 f32; dead after m2 -> mb16 (bf16 of m2) lives here
#define OFF_V2  5242880u            // (free)
#define OFF_M1  6291456u            // m1 bf16 (written directly by m1_kernel)
#define OFF_M2  7340032u            // m2 f32 (atomicAdd)
#define OFF_MG  8388608u            // mm1 bf16 [4096][512] = 2M ushorts = 1M float slots
#define OFF_A   9437184u            // RegionA: scores bf16 (33.5M ushorts) -> hid bf16 (33.5M ushorts)
#define OFF_W1B 26214400u           // bf16 w1: 262144 ushorts = 131072 float slots
#define OFF_W2B 26345472u           // bf16 w2: 131072 ushorts =  65536 float slots
#define OFF_WCB 26411008u           // bf16 Wc = W1b@merge_w: 512*256 ushorts = 65536 float slots

__device__ __forceinline__ float bf16_to_f(unsigned short u) {
    union { unsigned int ui; float f; } t; t.ui = ((unsigned int)u) << 16; return t.f;
}
__device__ __forceinline__ unsigned short f_to_bf16(float f) {
    union { float f; unsigned int u; } t; t.f = f;
    unsigned int u = t.u;
    u += 0x7fffu + ((u >> 16) & 1u);
    return (unsigned short)(u >> 16);
}

// ---------------- maxpool 4x4 (both branches) ----------------
__global__ __launch_bounds__(256) void pool_kernel(const float* __restrict__ x1,
                                                   const float* __restrict__ x2,
                                                   float* __restrict__ pooled) {
    int idx = blockIdx.x * 256 + threadIdx.x;           // 2^21 total
    int j = idx & 31, i = (idx >> 5) & 31, c = (idx >> 10) & 255, n = (idx >> 18) & 3, br = idx >> 20;
    const float* xp = br ? x2 : x1;
    const float* base = xp + (((size_t)(n * 256 + c) * 128 + i * 4) * 128 + j * 4);
    float m = -3.4e38f;
#pragma unroll
    for (int r = 0; r < 4; ++r) {
        float4 v = *(const float4*)(base + r * 128);
        m = fmaxf(m, fmaxf(fmaxf(v.x, v.y), fmaxf(v.z, v.w)));
    }
    pooled[(size_t)br * 1048576 + (size_t)(n * 256 + c) * 1024 + i * 32 + j] = m;
}

// ---------------- LayerNorm over channel dim, in place ----------------
__global__ __launch_bounds__(256) void lnc_kernel(float* __restrict__ p,
                                                  const float* __restrict__ g,
                                                  const float* __restrict__ b) {
    int bid = blockIdx.x;                                // (br,n,l)
    int l = bid & 1023, n = (bid >> 10) & 3, br = bid >> 12;
    int c = threadIdx.x;
    size_t idx = (size_t)br * 1048576 + (size_t)(n * 256 + c) * 1024 + l;
    float v = p[idx];
    __shared__ float red[256];
    red[c] = v; __syncthreads();
    for (int off = 128; off > 0; off >>= 1) { if (c < off) red[c] += red[c + off]; __syncthreads(); }
    float mean = red[0] / 256.f;
    __syncthreads();
    float d = v - mean;
    red[c] = d * d; __syncthreads();
    for (int off = 128; off > 0; off >>= 1) { if (c < off) red[c] += red[c + off]; __syncthreads(); }
    float var = red[0] / 256.f;
    float rstd = rsqrtf(var + EPSV);
    p[idx] = (v - mean) * rstd * g[c] + b[c];
}

// ---------------- depthwise 3x3 conv + BN ----------------
// which 0:q(p1,qk) 1:k(p2,qk) -> bf16 [n][l][c]; 2:v1(p1,v) -> f32 [n][l][c];
// which 3:v2(p2,v) -> bf16 TRANSPOSED [n][c][s] (lanes sweep l=s: coalesced)
__global__ __launch_bounds__(256) void dwbn_kernel(const float* __restrict__ p,
    const float* __restrict__ qkw, const float* __restrict__ qkg, const float* __restrict__ qkb,
    const float* __restrict__ qkm, const float* __restrict__ qkv,
    const float* __restrict__ vw, const float* __restrict__ vg, const float* __restrict__ vb,
    const float* __restrict__ vm, const float* __restrict__ vv,
    ushort_t* __restrict__ qk16, float* __restrict__ v1f, ushort_t* __restrict__ v2t16) {
    int which = blockIdx.y;
    int flat = blockIdx.x * 256 + threadIdx.x;     // 2^20
    int l = flat & 1023, c = (flat >> 10) & 255, n = flat >> 18;
    int br = which & 1;
    const float* w  = (which < 2) ? qkw : vw;
    const float* g  = (which < 2) ? qkg : vg;
    const float* bb = (which < 2) ? qkb : vb;
    const float* rm = (which < 2) ? qkm : vm;
    const float* rv = (which < 2) ? qkv : vv;
    int i = l >> 5, j = l & 31;
    const float* pin = p + (size_t)br * 1048576 + (size_t)(n * 256 + c) * 1024;
    float acc = 0.f;
#pragma unroll
    for (int ky = -1; ky <= 1; ++ky) {
        int yy = i + ky;
        if ((unsigned)yy < 32u) {
#pragma unroll
            for (int kx = -1; kx <= 1; ++kx) {
                int xx = j + kx;
                if ((unsigned)xx < 32u)
                    acc += pin[yy * 32 + xx] * w[c * 9 + (ky + 1) * 3 + (kx + 1)];
            }
        }
    }
    float sc = g[c] * rsqrtf(rv[c] + EPSV);
    float r = sc * (acc - rm[c]) + bb[c];
    if (which < 2)
        qk16[(size_t)which * 1048576 + (size_t)(n * 1024 + l) * 256 + c] = f_to_bf16(r);
    else if (which == 2)
        v1f[(size_t)(n * 1024 + l) * 256 + c] = r;
    else
        v2t16[(size_t)(n * 256 + c) * 1024 + l] = f_to_bf16(r);
}

// ---------------- fp32 -> bf16 conversion ----------------
__global__ __launch_bounds__(256) void cvt_kernel(const float* __restrict__ in,
                                                  ushort_t* __restrict__ out, int n) {
    int i = blockIdx.x * 256 + threadIdx.x;
    if (i < n) out[i] = f_to_bf16(in[i]);
}

// ---------------- Wc[512][256] = W1[:, 256:512] @ merge_w  (bf16 out) ----------------
__global__ __launch_bounds__(256) void wc_kernel(const float* __restrict__ w1,
                                                 const float* __restrict__ mw,
                                                 ushort_t* __restrict__ wcb) {
    int r = blockIdx.x, t = threadIdx.x;
    __shared__ float wrow[256];
    wrow[t] = w1[(size_t)r * 512 + 256 + t];
    __syncthreads();
    float acc = 0.f;
    for (int c = 0; c < 256; ++c) acc += wrow[c] * mw[(size_t)c * 256 + t];
    wcb[(size_t)r * 256 + t] = f_to_bf16(acc);
}

// ---------------- scores[n][h][l][s] (bf16) = t * Q_h K_h^T via MFMA bf16 ----------------
__global__ __launch_bounds__(256) void qk_mfma(const ushort_t* __restrict__ qb,
                                               const ushort_t* __restrict__ kb,
                                               ushort_t* __restrict__ scores) {
    int lt = blockIdx.x, st = blockIdx.y;
    int nh = blockIdx.z; int n = nh >> 3, h = nh & 7;
    int l0 = lt * 128, s0 = st * 128;
    __shared__ ushort_t Qs[128 * 32];
    __shared__ ushort_t Ks[128 * 32];
    int tid = threadIdx.x, lane = tid & 63, wv = tid >> 6;
    int wm = wv >> 1, wn = wv & 1;
    int ml = lane & 15, quad = lane >> 4;
#pragma unroll
    for (int c = 0; c < 2; ++c) {
        int g = c * 256 + tid;
        int row = g >> 2, seg = g & 3;
        const ushort_t* ga = qb + (size_t)(n * 1024 + l0 + row) * 256 + h * 32 + seg * 8;
        __builtin_amdgcn_global_load_lds((const __attribute__((address_space(1))) void*)ga,
                                         (__attribute__((address_space(3))) void*)&Qs[row * 32 + seg * 8], 16, 0, 0);
        const ushort_t* gk = kb + (size_t)(n * 1024 + s0 + row) * 256 + h * 32 + seg * 8;
        __builtin_amdgcn_global_load_lds((const __attribute__((address_space(1))) void*)gk,
                                         (__attribute__((address_space(3))) void*)&Ks[row * 32 + seg * 8], 16, 0, 0);
    }
    __syncthreads();
    f32x4 acc[4][4];
#pragma unroll
    for (int i = 0; i < 4; ++i)
#pragma unroll
        for (int j = 0; j < 4; ++j) acc[i][j] = (f32x4)(0.f);
    bf16x8 af[4], bfr[4];
#pragma unroll
    for (int mt = 0; mt < 4; ++mt)
        af[mt] = *(const bf16x8*)&Qs[(wm * 64 + mt * 16 + ml) * 32 + quad * 8];
#pragma unroll
    for (int nt = 0; nt < 4; ++nt)
        bfr[nt] = *(const bf16x8*)&Ks[(wn * 64 + nt * 16 + ml) * 32 + quad * 8];
#pragma unroll
    for (int mt = 0; mt < 4; ++mt)
#pragma unroll
        for (int nt = 0; nt < 4; ++nt)
            acc[mt][nt] = __builtin_amdgcn_mfma_f32_16x16x32_bf16(af[mt], bfr[nt], acc[mt][nt], 0, 0, 0);
    const float tsc = 0.17677669529663687f;   // 1/sqrt(32)
    ushort_t* sb = scores + (size_t)nh * 1024 * 1024;
#pragma unroll
    for (int mt = 0; mt < 4; ++mt)
#pragma unroll
        for (int nt = 0; nt < 4; ++nt) {
            int col = s0 + wn * 64 + nt * 16 + ml;
#pragma unroll
            for (int r = 0; r < 4; ++r) {
                int row = l0 + wm * 64 + mt * 16 + quad * 4 + r;
                unsigned short b = f_to_bf16(tsc * acc[mt][nt][r]);
                int partner = __shfl_xor((int)b, 1);
                if (!(ml & 1)) {
                    unsigned int pk = (unsigned int)b | ((unsigned int)partner << 16);
                    *(unsigned int*)&sb[(size_t)row * 1024 + col] = pk;
                }
            }
        }
}

// ---------------- m1[n,l,h,d] = softmax_s(sc) @ v2 -> bf16 out ----------------
__global__ __launch_bounds__(256) void m1_kernel(const ushort_t* __restrict__ scores,
                                                 const ushort_t* __restrict__ v2t,
                                                 ushort_t* __restrict__ m1out) {
    int lt = blockIdx.x, h = blockIdx.y, n = blockIdx.z;
    int tid = threadIdx.x, lane = tid & 63, wv = tid >> 6;
    int ml = lane & 15, quad = lane >> 4;
    int l0 = lt * 64 + wv * 16;
    const ushort_t* arow = scores + (size_t)((n * 8 + h) * 1024 + l0 + ml) * 1024 + quad * 8;
    const ushort_t* vb = v2t + (size_t)(n * 256 + h * 32) * 1024;
    const ushort_t* vrow0 = vb + (size_t)ml * 1024 + quad * 8;
    const ushort_t* vrow1 = vb + (size_t)(ml + 16) * 1024 + quad * 8;
    f32x4 acc0 = (f32x4)(0.f), acc1 = (f32x4)(0.f);
    float rsum = 0.f;
#pragma unroll 4
    for (int s0 = 0; s0 < 1024; s0 += 32) {
        bf16x8 sv = *(const bf16x8*)(arow + s0);
        float e0 = __expf(bf16_to_f((ushort_t)sv[0]));
        float e1 = __expf(bf16_to_f((ushort_t)sv[1]));
        float e2 = __expf(bf16_to_f((ushort_t)sv[2]));
        float e3 = __expf(bf16_to_f((ushort_t)sv[3]));
        float e4 = __expf(bf16_to_f((ushort_t)sv[4]));
        float e5 = __expf(bf16_to_f((ushort_t)sv[5]));
        float e6 = __expf(bf16_to_f((ushort_t)sv[6]));
        float e7 = __expf(bf16_to_f((ushort_t)sv[7]));
        rsum += ((e0 + e1) + (e2 + e3)) + ((e4 + e5) + (e6 + e7));
        bf16x8 af;
        af[0] = (short)f_to_bf16(e0); af[1] = (short)f_to_bf16(e1);
        af[2] = (short)f_to_bf16(e2); af[3] = (short)f_to_bf16(e3);
        af[4] = (short)f_to_bf16(e4); af[5] = (short)f_to_bf16(e5);
        af[6] = (short)f_to_bf16(e6); af[7] = (short)f_to_bf16(e7);
        bf16x8 b0 = *(const bf16x8*)(vrow0 + s0);
        bf16x8 b1 = *(const bf16x8*)(vrow1 + s0);
        acc0 = __builtin_amdgcn_mfma_f32_16x16x32_bf16(af, b0, acc0, 0, 0, 0);
        acc1 = __builtin_amdgcn_mfma_f32_16x16x32_bf16(af, b1, acc1, 0, 0, 0);
    }
    rsum += __shfl_xor(rsum, 16);
    rsum += __shfl_xor(rsum, 32);
#pragma unroll
    for (int r = 0; r < 4; ++r) {
        int row = quad * 4 + r;
        float inv = 1.f / __shfl(rsum, row);
        size_t ob = (size_t)(n * 1024 + l0 + row) * 256 + h * 32;
        m1out[ob + ml] = f_to_bf16(acc0[r] * inv);
        m1out[ob + 16 + ml] = f_to_bf16(acc1[r] * inv);
    }
}

// ---------------- m2[n,s,h,d] = sum_l softmax_h(sc)[l,s,h] * v1[l, h*32+d] ----------------
__global__ __launch_bounds__(256) void m2_kernel(const ushort_t* __restrict__ scores,
                                                 const float* __restrict__ v1,
                                                 float* __restrict__ m2out) {
    int st = blockIdx.x;       // 32 tiles of 32 s
    int lc = blockIdx.y;       // 8 chunks of 128 l
    int n  = blockIdx.z;
    int s0 = st * 32, tid = threadIdx.x;
    __shared__ float wls[8][8][32];   // [l_sub][h][s]
    float acc[32];
#pragma unroll
    for (int i = 0; i < 32; ++i) acc[i] = 0.f;
    int lA = tid >> 5, siA = tid & 31;
    int hB = tid >> 5;
    const ushort_t* sbase = scores + (size_t)n * 8 * 1024 * 1024;
    int lend = lc * 128 + 128;
    for (int lb = lc * 128; lb < lend; lb += 8) {
        int l = lb + lA;
        float e[8];
        float mx = -3.4e38f;
#pragma unroll
        for (int h = 0; h < 8; ++h) {
            e[h] = bf16_to_f(sbase[((size_t)h * 1024 + l) * 1024 + s0 + siA]);
            mx = fmaxf(mx, e[h]);
        }
        float sum = 0.f;
#pragma unroll
        for (int h = 0; h < 8; ++h) { e[h] = expf(e[h] - mx); sum += e[h]; }
        float inv = 1.f / sum;
#pragma unroll
        for (int h = 0; h < 8; ++h) wls[lA][h][siA] = e[h] * inv;
        __syncthreads();
#pragma unroll
        for (int ls = 0; ls < 8; ++ls) {
            float v1v = v1[(size_t)(n * 1024 + lb + ls) * 256 + tid];
#pragma unroll
            for (int s4 = 0; s4 < 8; ++s4) {
                float4 w4 = *(const float4*)&wls[ls][hB][s4 * 4];
                acc[s4 * 4]     += w4.x * v1v;
                acc[s4 * 4 + 1] += w4.y * v1v;
                acc[s4 * 4 + 2] += w4.z * v1v;
                acc[s4 * 4 + 3] += w4.w * v1v;
            }
        }
        __syncthreads();
    }
#pragma unroll
    for (int ss = 0; ss < 32; ++ss)
        atomicAdd(&m2out[(size_t)(n * 1024 + s0 + ss) * 256 + tid], acc[ss]);
}

// ---------------- MFMA bf16 GEMM (runtime K): C[M,N] = act(A[M,K] @ B[N,K]^T) ----------------
__global__ __launch_bounds__(256) void mfma_gemm(const ushort_t* __restrict__ A,
                                                 const ushort_t* __restrict__ B,
                                                 float* __restrict__ Of,
                                                 ushort_t* __restrict__ Oh,
                                                 int N, int relu, int K) {
    int m0 = blockIdx.x * 128, n0 = blockIdx.y * 128;
    int tid = threadIdx.x;
    __shared__ ushort_t Al[128 * 32];
    __shared__ ushort_t Bl[128 * 32];
    int lane = tid & 63;
    int wv = tid >> 6;
    int wm = wv >> 1, wn = wv & 1;
    int ml = lane & 15, quad = lane >> 4;
    f32x4 acc[4][4];
#pragma unroll
    for (int i = 0; i < 4; ++i)
#pragma unroll
        for (int j = 0; j < 4; ++j) acc[i][j] = (f32x4)(0.f);

    for (int k0 = 0; k0 < K; k0 += 32) {
#pragma unroll
        for (int c = 0; c < 2; ++c) {
            int g = c * 256 + tid;
            int row = g >> 2, seg = g & 3;
            const ushort_t* ga = A + (size_t)(m0 + row) * K + k0 + seg * 8;
            __builtin_amdgcn_global_load_lds((const __attribute__((address_space(1))) void*)ga,
                                             (__attribute__((address_space(3))) void*)&Al[g * 8], 16, 0, 0);
            const ushort_t* gb = B + (size_t)(n0 + row) * K + k0 + seg * 8;
            __builtin_amdgcn_global_load_lds((const __attribute__((address_space(1))) void*)gb,
                                             (__attribute__((address_space(3))) void*)&Bl[g * 8], 16, 0, 0);
        }
        __syncthreads();
        bf16x8 af[4], bfr[4];
#pragma unroll
        for (int mt = 0; mt < 4; ++mt)
            af[mt] = *(const bf16x8*)&Al[(wm * 64 + mt * 16 + ml) * 32 + quad * 8];
#pragma unroll
        for (int nt = 0; nt < 4; ++nt)
            bfr[nt] = *(const bf16x8*)&Bl[(wn * 64 + nt * 16 + ml) * 32 + quad * 8];
#pragma unroll
        for (int mt = 0; mt < 4; ++mt)
#pragma unroll
            for (int nt = 0; nt < 4; ++nt)
                acc[mt][nt] = __builtin_amdgcn_mfma_f32_16x16x32_bf16(af[mt], bfr[nt], acc[mt][nt], 0, 0, 0);
        __syncthreads();
    }
#pragma unroll
    for (int mt = 0; mt < 4; ++mt) {
#pragma unroll
        for (int nt = 0; nt < 4; ++nt) {
            int col = n0 + wn * 64 + nt * 16 + ml;
#pragma unroll
            for (int r = 0; r < 4; ++r) {
                int row = m0 + wm * 64 + mt * 16 + quad * 4 + r;
                float v = acc[mt][nt][r];
                if (relu) v = fmaxf(v, 0.f);
                if (Oh) Oh[(size_t)row * N + col] = f_to_bf16(v);
                else    Of[(size_t)row * N + col] = v;
            }
        }
    }
}

// ---------------- fused GEMM1: hid[pix][512] = relu(x_nhwc @ W1a^T + up(mm1)) ----------------
// Block: 64 pixels x ALL 512 out-cols, 8 waves (512 thr), K=256. x read ONCE.
// A (x) transposed NCHW->[pix][c] in-kernel via padded t32 tile -> XOR-swizzled bf16 A-LDS.
// B (W1 rows, k<256) staged via global_load_lds. up(mm1) added in epilogue.
__global__ __launch_bounds__(512) void gemm1_fused(const float* __restrict__ x,
                                                   const ushort_t* __restrict__ W1,
                                                   const ushort_t* __restrict__ mm1,
                                                   ushort_t* __restrict__ hid) {
    __shared__ char smem[65536];
    ushort_t* Bl  = (ushort_t*)(smem + 32768);   // [512][32] bf16 = 32KB
    float* t32    = (float*)(smem + 32768);      // [32][68] f32 = 8704B (overlaps Bl, prologue only)
    int m0 = blockIdx.x * 64;
    int n = m0 >> 14, y = (m0 >> 7) & 127, x0 = m0 & 127;
    int tid = threadIdx.x, lane = tid & 63;
    int wv = tid >> 6, ml = lane & 15, quad = lane >> 4;

    // ---- prologue: transpose x[n][0..255][y][x0..x0+63] -> swizzled A [pix][c]
    const float* xrow = x + ((size_t)(n * 256) * 128 + y) * 128 + x0;
    for (int cb = 0; cb < 256; cb += 32) {
        __syncthreads();
        {
            int l16 = tid & 15, cl = tid >> 4;   // 32 c-rows x 16 x-quads
            float4 v = *(const float4*)(xrow + (size_t)(cb + cl) * 16384 + l16 * 4);
            *(float4*)&t32[cl * 68 + l16 * 4] = v;
        }
        __syncthreads();
        {
            int clw = tid & 31, pg = tid >> 5;   // 16 pixel-groups of 4
#pragma unroll
            for (int k = 0; k < 4; ++k) {
                int pix = pg * 4 + k;
                float v = t32[clw * 68 + pix];
                unsigned byte = ((unsigned)(pix * 256 + cb + clw) * 2u) ^ ((unsigned)(pix & 7) << 4);
                *(ushort_t*)(smem + byte) = f_to_bf16(v);
            }
        }
    }
    __syncthreads();

    // ---- K-loop: 8 steps of 32
    f32x4 acc[4][4];
#pragma unroll
    for (int i = 0; i < 4; ++i)
#pragma unroll
        for (int j = 0; j < 4; ++j) acc[i][j] = (f32x4)(0.f);
    for (int k0 = 0; k0 < 256; k0 += 32) {
#pragma unroll
        for (int c = 0; c < 4; ++c) {   // stage B: 512 rows x 32 k
            int g = c * 512 + tid;
            int row = g >> 2, seg = g & 3;
            const ushort_t* gb = W1 + (size_t)row * 512 + k0 + seg * 8;
            __builtin_amdgcn_global_load_lds((const __attribute__((address_space(1))) void*)gb,
                                             (__attribute__((address_space(3))) void*)&Bl[g * 8], 16, 0, 0);
        }
        __syncthreads();
        bf16x8 af[4], bfr[4];
#pragma unroll
        for (int mt = 0; mt < 4; ++mt) {
            int pix = mt * 16 + ml;
            unsigned byte = ((unsigned)(pix * 256 + k0 + quad * 8) * 2u) ^ ((unsigned)(pix & 7) << 4);
            af[mt] = *(const bf16x8*)(smem + byte);
        }
#pragma unroll
        for (int nt = 0; nt < 4; ++nt)
            bfr[nt] = *(const bf16x8*)&Bl[(wv * 64 + nt * 16 + ml) * 32 + quad * 8];
#pragma unroll
        for (int mt = 0; mt < 4; ++mt)
#pragma unroll
            for (int nt = 0; nt < 4; ++nt)
                acc[mt][nt] = __builtin_amdgcn_mfma_f32_16x16x32_bf16(af[mt], bfr[nt], acc[mt][nt], 0, 0, 0);
        __syncthreads();
    }

    // ---- epilogue: add bilinear-up(mm1), relu, write hid bf16
    float iy = y * 0.25f - 0.375f;
    int y0i = (int)floorf(iy);
    float fy = iy - (float)y0i;
    int y0c = max(y0i, 0), y1c = min(y0i + 1, 31);
    const ushort_t* mb0 = mm1 + (size_t)(n * 1024 + y0c * 32) * 512;
    const ushort_t* mb1 = mm1 + (size_t)(n * 1024 + y1c * 32) * 512;
#pragma unroll
    for (int mt = 0; mt < 4; ++mt)
#pragma unroll
        for (int r = 0; r < 4; ++r) {
            int p = mt * 16 + quad * 4 + r;
            int xx = x0 + p;
            float ix = xx * 0.25f - 0.375f;
            int x0i = (int)floorf(ix);
            float fx = ix - (float)x0i;
            int xc0 = max(x0i, 0), xc1 = min(x0i + 1, 31);
#pragma unroll
            for (int nt = 0; nt < 4; ++nt) {
                int col = wv * 64 + nt * 16 + ml;
                float v00 = bf16_to_f(mb0[(size_t)xc0 * 512 + col]);
                float v01 = bf16_to_f(mb0[(size_t)xc1 * 512 + col]);
                float v10 = bf16_to_f(mb1[(size_t)xc0 * 512 + col]);
                float v11 = bf16_to_f(mb1[(size_t)xc1 * 512 + col]);
                float up = (1.f - fy) * ((1.f - fx) * v00 + fx * v01)
                         + fy * ((1.f - fx) * v10 + fx * v11);
                float v = fmaxf(acc[mt][nt][r] + up, 0.f);
                hid[(size_t)(m0 + p) * 512 + col] = f_to_bf16(v);
            }
        }
}

// ---------------- fused GEMM2 + LN + residual + NCHW write ----------------
__global__ __launch_bounds__(256) void gemm2_ln(const ushort_t* __restrict__ hid,
                                                const ushort_t* __restrict__ W2,
                                                const float* __restrict__ xin,
                                                const float* __restrict__ g2,
                                                const float* __restrict__ b2,
                                                float* __restrict__ outp) {
    __shared__ char smem[35584];
    ushort_t* Al = (ushort_t*)smem;              // [64][32] bf16 = 4KB
    ushort_t* Bl = (ushort_t*)(smem + 4096);     // [256][32] bf16 = 16KB
    int m0 = blockIdx.x * 64;
    int tid = threadIdx.x, lane = tid & 63, wv = tid >> 6;
    int ml = lane & 15, quad = lane >> 4;
    f32x4 acc[4][4];
#pragma unroll
    for (int i = 0; i < 4; ++i)
#pragma unroll
        for (int j = 0; j < 4; ++j) acc[i][j] = (f32x4)(0.f);

    for (int k0 = 0; k0 < 512; k0 += 32) {
        {
            int row = tid >> 2, seg = tid & 3;
            const ushort_t* ga = hid + (size_t)(m0 + row) * 512 + k0 + seg * 8;
            __builtin_amdgcn_global_load_lds((const __attribute__((address_space(1))) void*)ga,
                                             (__attribute__((address_space(3))) void*)&Al[tid * 8], 16, 0, 0);
        }
#pragma unroll
        for (int c = 0; c < 4; ++c) {
            int g = c * 256 + tid;
            int row = g >> 2, seg = g & 3;
            const ushort_t* gb = W2 + (size_t)row * 512 + k0 + seg * 8;
            __builtin_amdgcn_global_load_lds((const __attribute__((address_space(1))) void*)gb,
                                             (__attribute__((address_space(3))) void*)&Bl[g * 8], 16, 0, 0);
        }
        __syncthreads();
        bf16x8 af[4], bfr[4];
#pragma unroll
        for (int mt = 0; mt < 4; ++mt)
            af[mt] = *(const bf16x8*)&Al[(mt * 16 + ml) * 32 + quad * 8];
#pragma unroll
        for (int nt = 0; nt < 4; ++nt)
            bfr[nt] = *(const bf16x8*)&Bl[(wv * 64 + nt * 16 + ml) * 32 + quad * 8];
#pragma unroll
        for (int mt = 0; mt < 4; ++mt)
#pragma unroll
            for (int nt = 0; nt < 4; ++nt)
                acc[mt][nt] = __builtin_amdgcn_mfma_f32_16x16x32_bf16(af[mt], bfr[nt], acc[mt][nt], 0, 0, 0);
        __syncthreads();
    }
    float* redS = (float*)smem;            // [64][4]
    float* redQ = (float*)(smem + 1024);   // [64][4]
    float* muA  = (float*)(smem + 2048);   // [64]
    float* rsA  = (float*)(smem + 2304);   // [64]
    float* olds = (float*)(smem + 2560);   // [64][129]
#pragma unroll
    for (int mt = 0; mt < 4; ++mt)
#pragma unroll
        for (int r = 0; r < 4; ++r) {
            float s = 0.f, q = 0.f;
#pragma unroll
            for (int nt = 0; nt < 4; ++nt) { float v = acc[mt][nt][r]; s += v; q += v * v; }
            s += __shfl_xor(s, 1); s += __shfl_xor(s, 2); s += __shfl_xor(s, 4); s += __shfl_xor(s, 8);
            q += __shfl_xor(q, 1); q += __shfl_xor(q, 2); q += __shfl_xor(q, 4); q += __shfl_xor(q, 8);
            if (ml == 0) {
                int row = mt * 16 + quad * 4 + r;
                redS[row * 4 + wv] = s; redQ[row * 4 + wv] = q;
            }
        }
    __syncthreads();
    if (tid < 64) {
        float S = redS[tid * 4] + redS[tid * 4 + 1] + redS[tid * 4 + 2] + redS[tid * 4 + 3];
        float Q = redQ[tid * 4] + redQ[tid * 4 + 1] + redQ[tid * 4 + 2] + redQ[tid * 4 + 3];
        float mu = S * (1.f / 256.f);
        float var = Q * (1.f / 256.f) - mu * mu;
        muA[tid] = mu; rsA[tid] = rsqrtf(var + EPSV);
    }
    __syncthreads();
    int n = m0 >> 14, y = (m0 >> 7) & 127, x0 = m0 & 127;
    int cg = tid >> 5, xi = tid & 31;
#pragma unroll
    for (int half = 0; half < 2; ++half) {
        if ((wv >> 1) == half) {
#pragma unroll
            for (int mt = 0; mt < 4; ++mt)
#pragma unroll
                for (int r = 0; r < 4; ++r) {
                    int row = mt * 16 + quad * 4 + r;
                    float mu = muA[row], rs = rsA[row];
#pragma unroll
                    for (int nt = 0; nt < 4; ++nt) {
                        int col = wv * 64 + nt * 16 + ml;
                        int lc = col - half * 128;
                        olds[row * 129 + lc] = (acc[mt][nt][r] - mu) * rs * g2[col] + b2[col];
                    }
                }
        }
        __syncthreads();
        for (int cc = 0; cc < 16; ++cc) {
            int lc = cc * 8 + cg;
            int c = half * 128 + lc;
            size_t gbase = ((size_t)(n * 256 + c) * 128 + y) * 128 + x0;
#pragma unroll
            for (int xc = 0; xc < 2; ++xc) {
                int p = xc * 32 + xi;
                outp[gbase + p] = xin[gbase + p] + olds[p * 129 + lc];
            }
        }
        __syncthreads();
    }
}

extern "C" void kernel_launch(void* const* d_in, const int* in_sizes, int n_in,
                              void* d_out, int out_size, void* d_ws, size_t ws_size,
                              hipStream_t stream) {
    (void)in_sizes; (void)n_in; (void)out_size; (void)ws_size;
    const float* x1     = (const float*)d_in[0];
    const float* x2     = (const float*)d_in[1];
    const float* qk_w   = (const float*)d_in[2];
    const float* qk_g   = (const float*)d_in[3];
    const float* qk_b   = (const float*)d_in[4];
    const float* qk_m   = (const float*)d_in[5];
    const float* qk_v   = (const float*)d_in[6];
    const float* v_w    = (const float*)d_in[7];
    const float* v_g    = (const float*)d_in[8];
    const float* v_b    = (const float*)d_in[9];
    const float* v_m    = (const float*)d_in[10];
    const float* v_v    = (const float*)d_in[11];
    const float* ln1_g  = (const float*)d_in[12];
    const float* ln1_b  = (const float*)d_in[13];
    const float* ln2_g  = (const float*)d_in[14];
    const float* ln2_b  = (const float*)d_in[15];
    const float* merge_w = (const float*)d_in[16];
    const float* mlp_w1 = (const float*)d_in[17];
    const float* mlp_w2 = (const float*)d_in[18];

    float* ws      = (float*)d_ws;
    float* pooled  = ws + OFF_P;
    float* v1buf   = ws + OFF_V1;
    float* m2buf   = ws + OFF_M2;
    ushort_t* qkb16 = (ushort_t*)(ws + OFF_Q);    // q bf16 then k bf16 (old f32 q region)
    ushort_t* v2tb = (ushort_t*)(ws + OFF_K);     // v2 transposed bf16 (old f32 k region)
    ushort_t* m1b16 = (ushort_t*)(ws + OFF_M1);   // m1 bf16, written directly
    ushort_t* mb16  = (ushort_t*)(ws + OFF_V1);   // bf16 of m2 (v1 dead after m2)
    ushort_t* mm1b  = (ushort_t*)(ws + OFF_MG);   // mm1 bf16 [4096][512]
    ushort_t* scores16 = (ushort_t*)(ws + OFF_A); // scores bf16 -> hid bf16 (stream-ordered reuse)
    ushort_t* hid  = (ushort_t*)(ws + OFF_A);
    ushort_t* w1b  = (ushort_t*)(ws + OFF_W1B);
    ushort_t* w2b  = (ushort_t*)(ws + OFF_W2B);
    ushort_t* wcb  = (ushort_t*)(ws + OFF_WCB);
    float* outp    = (float*)d_out;

    hipMemsetAsync(m2buf, 0, 1048576 * sizeof(float), stream);

    wc_kernel<<<512, 256, 0, stream>>>(mlp_w1, merge_w, wcb);
    pool_kernel<<<8192, 256, 0, stream>>>(x1, x2, pooled);
    lnc_kernel<<<8192, 256, 0, stream>>>(pooled, ln1_g, ln1_b);
    dwbn_kernel<<<dim3(4096, 4), 256, 0, stream>>>(pooled,
        qk_w, qk_g, qk_b, qk_m, qk_v, v_w, v_g, v_b, v_m, v_v,
        qkb16, v1buf, v2tb);
    qk_mfma<<<dim3(8, 8, 32), 256, 0, stream>>>(qkb16, qkb16 + 1048576, scores16);
    m1_kernel<<<dim3(16, 8, 4), 256, 0, stream>>>(scores16, v2tb, m1b16);
    m2_kernel<<<dim3(32, 8, 4), 256, 0, stream>>>(scores16, v1buf, m2buf);

    cvt_kernel<<<1024, 256, 0, stream>>>(mlp_w1, w1b, 262144);
    cvt_kernel<<<512, 256, 0, stream>>>(mlp_w2, w2b, 131072);

    for (int br = 0; br < 2; ++br) {
        const float* xin = br ? x2 : x1;
        const ushort_t* mmb;
        if (br == 0) {
            mmb = m1b16;
        } else {
            cvt_kernel<<<4096, 256, 0, stream>>>(m2buf, mb16, 1048576);
            mmb = mb16;
        }
        // mm1[4096][512] = m @ Wc^T  (M=4096, N=512, K=256)
        mfma_gemm<<<dim3(32, 4), 256, 0, stream>>>(mmb, wcb, nullptr, mm1b, 512, 0, 256);
        gemm1_fused<<<1024, 512, 0, stream>>>(xin, w1b, mm1b, hid);
        gemm2_ln<<<1024, 256, 0, stream>>>(hid, w2b, xin, ln2_g, ln2_b,
                                           outp + (size_t)br * 16777216);
    }
}